// Round 6
// baseline (733.606 us; speedup 1.0000x reference)
//
#include <hip/hip_runtime.h>

#define NN   102400
#define EE   819200
#define GG   512
#define NPG  200
#define DD   128
#define TT   64
#define BB   8
#define LL   4
#define CHK  50     // nodes per chunk (4 chunks per graph)

typedef unsigned int uint;

static __device__ __forceinline__ float wave_sum64(float v) {
#pragma unroll
    for (int off = 32; off > 0; off >>= 1) v += __shfl_xor(v, off, 64);
    return v;
}

// ---------------- CSR build (sort edges by dst node) ----------------

__global__ void k_ncount(const int* __restrict__ dst, int* __restrict__ cnt) {
    int e = blockIdx.x * blockDim.x + threadIdx.x;
    if (e < EE) atomicAdd(&cnt[dst[e]], 1);
}

__global__ __launch_bounds__(64) void k_gsum(const int* __restrict__ cnt,
                                             int* __restrict__ gcnt) {
    int g = blockIdx.x, t = threadIdx.x;
    int s = 0;
    for (int i = t; i < NPG; i += 64) s += cnt[g * NPG + i];
#pragma unroll
    for (int off = 32; off > 0; off >>= 1) s += __shfl_xor(s, off, 64);
    if (t == 0) gcnt[g] = s;
}

__global__ void k_gprefix(const int* __restrict__ gcnt, int* __restrict__ gbase) {
    __shared__ int sm[GG];
    int t = threadIdx.x;
    int c = gcnt[t];
    sm[t] = c;
    __syncthreads();
    for (int d = 1; d < GG; d <<= 1) {
        int v = (t >= d) ? sm[t - d] : 0;
        __syncthreads();
        sm[t] += v;
        __syncthreads();
    }
    gbase[t] = sm[t] - c;
    if (t == GG - 1) gbase[GG] = sm[t];
}

__global__ __launch_bounds__(256) void k_nscan(const int* __restrict__ cnt,
                                               const int* __restrict__ gbase,
                                               int* __restrict__ node_off,
                                               int* __restrict__ cursorN) {
    int g = blockIdx.x, t = threadIdx.x;
    __shared__ int sm[256];
    int c = (t < NPG) ? cnt[g * NPG + t] : 0;
    sm[t] = c;
    __syncthreads();
    for (int d = 1; d < 256; d <<= 1) {
        int v = (t >= d) ? sm[t - d] : 0;
        __syncthreads();
        sm[t] += v;
        __syncthreads();
    }
    if (t < NPG) {
        int off = gbase[g] + sm[t] - c;
        node_off[g * NPG + t] = off;
        cursorN[g * NPG + t] = off;
    }
    if (g == GG - 1 && t == 0) node_off[NN] = gbase[GG];
}

__global__ void k_escatter(const int* __restrict__ src, const int* __restrict__ dst,
                           const int* __restrict__ cnt, int* __restrict__ cursorN,
                           uint2* __restrict__ epackN) {
    int e = blockIdx.x * blockDim.x + threadIdx.x;
    if (e >= EE) return;
    int s = src[e], d = dst[e];
    int pos = atomicAdd(&cursorN[d], 1);
    float w = rsqrtf((float)(cnt[s] + 1)) * rsqrtf((float)(cnt[d] + 1));
    epackN[pos] = make_uint2((uint)s, __float_as_uint(w));  // GLOBAL src id
}

// ---------------- GCN (no LDS staging; L2-resident gathers; chunked grids) ---------

// layer 1: agg x (2-wide) + 2->64 transform + bias/relu/LN, wave per node
__global__ __launch_bounds__(256) void k_gcn1(
    const float* __restrict__ x, const float* __restrict__ W1,
    const float* __restrict__ gb1, const float* __restrict__ lng,
    const float* __restrict__ lnb, const int* __restrict__ cnt,
    const int* __restrict__ node_off, const uint2* __restrict__ epackN,
    float* __restrict__ hout) {
    int c = blockIdx.x;                 // 2048 chunks
    int n0 = c * CHK;
    __shared__ int noff[CHK + 1];
    __shared__ float dinv[CHK];
    int tid = threadIdx.x, j = tid & 63, wid = tid >> 6;
    if (tid <= CHK) noff[tid] = node_off[n0 + tid];
    if (tid < CHK) dinv[tid] = 1.f / (float)(cnt[n0 + tid] + 1);
    __syncthreads();
    const float2* x2 = (const float2*)x;
    float w0 = W1[j], w1 = W1[64 + j];
    float gbj = gb1[j], lgj = lng[j], lbj = lnb[j];
    for (int i = wid; i < CHK; i += 4) {
        int n = n0 + i;
        float2 xv = x2[n];
        float ax = xv.x * dinv[i], ay = xv.y * dinv[i];
        int e0 = noff[i], e1 = noff[i + 1];
        for (int e = e0; e < e1; ++e) {
            uint2 ed = epackN[e];
            float w = __uint_as_float(ed.y);
            float2 xe = x2[ed.x];
            ax += xe.x * w;
            ay += xe.y * w;
        }
        float u = fmaxf(ax * w0 + ay * w1 + gbj, 0.f);
        float mean = wave_sum64(u) * (1.f / 64.f);
        float dv = u - mean;
        float var = wave_sum64(dv * dv) * (1.f / 64.f);
        hout[(size_t)n * 64 + j] = dv * rsqrtf(var + 1e-5f) * lgj + lbj;
    }
}

// 64-wide aggregation z = A_hat * t (no LN), wave per node, lane = feature
__global__ __launch_bounds__(256) void k_agg(
    const float* __restrict__ t, const int* __restrict__ cnt,
    const int* __restrict__ node_off, const uint2* __restrict__ epackN,
    float* __restrict__ z) {
    int c = blockIdx.x;
    int n0 = c * CHK;
    __shared__ int noff[CHK + 1];
    __shared__ float dinv[CHK];
    int tid = threadIdx.x, j = tid & 63, wid = tid >> 6;
    if (tid <= CHK) noff[tid] = node_off[n0 + tid];
    if (tid < CHK) dinv[tid] = 1.f / (float)(cnt[n0 + tid] + 1);
    __syncthreads();
    for (int i = wid; i < CHK; i += 4) {
        int n = n0 + i;
        float acc = t[(size_t)n * 64 + j] * dinv[i];
        int e0 = noff[i], e1 = noff[i + 1];
        int e = e0;
        for (; e + 1 < e1; e += 2) {
            uint2 ed0 = epackN[e], ed1 = epackN[e + 1];
            acc += t[(size_t)ed0.x * 64 + j] * __uint_as_float(ed0.y);
            acc += t[(size_t)ed1.x * 64 + j] * __uint_as_float(ed1.y);
        }
        if (e < e1) {
            uint2 ed = epackN[e];
            acc += t[(size_t)ed.x * 64 + j] * __uint_as_float(ed.y);
        }
        z[(size_t)n * 64 + j] = acc;
    }
}

// h = LN(relu(z @ W + b)) : 64-node tiles, W in registers, wave per node
__global__ __launch_bounds__(256) void k_lin_ln(
    const float* __restrict__ z, const float* __restrict__ W,
    const float* __restrict__ gb, const float* __restrict__ lng,
    const float* __restrict__ lnb, float* __restrict__ hout) {
    int nb = blockIdx.x;  // 1600 blocks x 64 nodes
    __shared__ float hs[64 * 64];
    __shared__ float ws[64 * 64];
    int tid = threadIdx.x, j = tid & 63, wid = tid >> 6;
    const float4* in4 = (const float4*)(z + (size_t)nb * 64 * 64);
    for (int i = tid; i < 1024; i += 256) {
        ((float4*)hs)[i] = in4[i];
        ((float4*)ws)[i] = ((const float4*)W)[i];
    }
    __syncthreads();
    float wreg[64];
#pragma unroll
    for (int k = 0; k < 64; ++k) wreg[k] = ws[k * 64 + j];
    float gbj = gb[j], lgj = lng[j], lbj = lnb[j];
    float* ob = hout + (size_t)nb * 64 * 64;
    for (int i = wid; i < 64; i += 4) {
        const float4* hrow = (const float4*)&hs[i * 64];
        float a0 = 0.f, a1 = 0.f;
#pragma unroll
        for (int k4 = 0; k4 < 16; k4 += 2) {
            float4 h0 = hrow[k4], h1 = hrow[k4 + 1];
            a0 += h0.x * wreg[4 * k4] + h0.y * wreg[4 * k4 + 1] +
                  h0.z * wreg[4 * k4 + 2] + h0.w * wreg[4 * k4 + 3];
            a1 += h1.x * wreg[4 * k4 + 4] + h1.y * wreg[4 * k4 + 5] +
                  h1.z * wreg[4 * k4 + 6] + h1.w * wreg[4 * k4 + 7];
        }
        float u = fmaxf(a0 + a1 + gbj, 0.f);
        float mean = wave_sum64(u) * (1.f / 64.f);
        float dv = u - mean;
        float var = wave_sum64(dv * dv) * (1.f / 64.f);
        ob[i * 64 + j] = dv * rsqrtf(var + 1e-5f) * lgj + lbj;
    }
}

// layer-3 aggregation + partial mean pooling (atomic into zeroed pooledT)
__global__ __launch_bounds__(256) void k_agg_pool(
    const float* __restrict__ t, const int* __restrict__ cnt,
    const int* __restrict__ node_off, const uint2* __restrict__ epackN,
    float* __restrict__ pooledT) {
    int c = blockIdx.x;
    int g = c >> 2;
    int n0 = c * CHK;
    __shared__ int noff[CHK + 1];
    __shared__ float dinv[CHK];
    __shared__ float red[4][64];
    int tid = threadIdx.x, j = tid & 63, wid = tid >> 6;
    if (tid <= CHK) noff[tid] = node_off[n0 + tid];
    if (tid < CHK) dinv[tid] = 1.f / (float)(cnt[n0 + tid] + 1);
    __syncthreads();
    float rsum = 0.f;
    for (int i = wid; i < CHK; i += 4) {
        int n = n0 + i;
        float acc = t[(size_t)n * 64 + j] * dinv[i];
        int e0 = noff[i], e1 = noff[i + 1];
        int e = e0;
        for (; e + 1 < e1; e += 2) {
            uint2 ed0 = epackN[e], ed1 = epackN[e + 1];
            acc += t[(size_t)ed0.x * 64 + j] * __uint_as_float(ed0.y);
            acc += t[(size_t)ed1.x * 64 + j] * __uint_as_float(ed1.y);
        }
        if (e < e1) {
            uint2 ed = epackN[e];
            acc += t[(size_t)ed.x * 64 + j] * __uint_as_float(ed.y);
        }
        rsum += acc;
    }
    red[wid][j] = rsum;
    __syncthreads();
    if (tid < 64)
        atomicAdd(&pooledT[j * GG + g],
                  (red[0][j] + red[1][j] + red[2][j] + red[3][j]) * (1.f / NPG));
}

// pooled(64) @ W3 -> (128) + b3 + PE, writes seqT[d][g]
__global__ __launch_bounds__(512) void k_emb(
    const float* __restrict__ pooledT, const float* __restrict__ W3,
    const float* __restrict__ b3, float* __restrict__ seqT) {
    int d = blockIdx.x, g = threadIdx.x;
    __shared__ float wcol[64];
    if (g < 64) wcol[g] = W3[g * DD + d];
    __syncthreads();
    float acc = b3[d];
#pragma unroll 8
    for (int k = 0; k < 64; ++k) acc += pooledT[k * GG + g] * wcol[k];
    float freq = expf((float)(d & ~1) * (-9.210340371976184f / 128.f));
    float ang = (float)(g & (TT - 1)) * freq;
    acc += (d & 1) ? cosf(ang) : sinf(ang);
    seqT[d * GG + g] = acc;
}

// ---------------- Transformer (transposed activations: [feat][512]) ----------------

template <int K, bool RELU, bool RES>
__global__ __launch_bounds__(128) void k_gemmT(
    const float* __restrict__ AT, const float* __restrict__ W,
    const float* __restrict__ bias, const float* __restrict__ resP,
    float* __restrict__ C) {
    int o = blockIdx.x, t = threadIdx.x;
    __shared__ float ws[K];
    for (int k = t; k < K; k += 128) ws[k] = W[o * K + k];
    __syncthreads();
    const float4* A4 = (const float4*)AT;
    float4 acc = make_float4(0.f, 0.f, 0.f, 0.f);
#pragma unroll 8
    for (int k = 0; k < K; ++k) {
        float w = ws[k];
        float4 a = A4[k * 128 + t];
        acc.x += a.x * w; acc.y += a.y * w; acc.z += a.z * w; acc.w += a.w * w;
    }
    float bv = bias[o];
    acc.x += bv; acc.y += bv; acc.z += bv; acc.w += bv;
    if (RELU) {
        acc.x = fmaxf(acc.x, 0.f); acc.y = fmaxf(acc.y, 0.f);
        acc.z = fmaxf(acc.z, 0.f); acc.w = fmaxf(acc.w, 0.f);
    }
    if (RES) {
        float4 r = ((const float4*)resP)[o * 128 + t];
        acc.x += r.x; acc.y += r.y; acc.z += r.z; acc.w += r.w;
    }
    ((float4*)C)[o * 128 + t] = acc;
}

__global__ __launch_bounds__(64) void k_attnT(const float* __restrict__ qkvT,
                                              float* __restrict__ aT) {
    int b = blockIdx.x >> 2, h = blockIdx.x & 3;
    int t = threadIdx.x;
    __shared__ float Ks[32][TT], Vs[32][TT];
    __shared__ float sp[TT][TT + 1];
    int col = b * TT + t;
#pragma unroll
    for (int dh = 0; dh < 32; ++dh) {
        Ks[dh][t] = qkvT[(DD + h * 32 + dh) * GG + col];
        Vs[dh][t] = qkvT[(2 * DD + h * 32 + dh) * GG + col];
    }
    float q[32];
#pragma unroll
    for (int dh = 0; dh < 32; ++dh) q[dh] = qkvT[(h * 32 + dh) * GG + col];
    __syncthreads();
    const float scale = 0.17677669529663687f;  // 1/sqrt(32)
    for (int jj = 0; jj < TT; ++jj) {
        float a = 0.f;
#pragma unroll
        for (int dh = 0; dh < 32; ++dh) a += q[dh] * Ks[dh][jj];
        sp[t][jj] = a * scale;
    }
    float mx = -1e30f;
    for (int jj = 0; jj < TT; ++jj) mx = fmaxf(mx, sp[t][jj]);
    float ssum = 0.f;
    for (int jj = 0; jj < TT; ++jj) {
        float e2 = expf(sp[t][jj] - mx);
        sp[t][jj] = e2;
        ssum += e2;
    }
    float inv = 1.f / ssum;
    float o[32];
#pragma unroll
    for (int dh = 0; dh < 32; ++dh) o[dh] = 0.f;
    for (int jj = 0; jj < TT; ++jj) {
        float s = sp[t][jj] * inv;
#pragma unroll
        for (int dh = 0; dh < 32; ++dh) o[dh] += s * Vs[dh][jj];
    }
#pragma unroll
    for (int dh = 0; dh < 32; ++dh) aT[(h * 32 + dh) * GG + col] = o[dh];
}

__global__ void k_lnT(float* __restrict__ S, const float* __restrict__ g,
                      const float* __restrict__ bl) {
    int r = blockIdx.x * blockDim.x + threadIdx.x;  // one lane per row
    float sum = 0.f, sq = 0.f;
    for (int d = 0; d < DD; ++d) {
        float v = S[d * GG + r];
        sum += v;
        sq += v * v;
    }
    float mean = sum * (1.f / DD);
    float var = sq * (1.f / DD) - mean * mean;
    float rstd = rsqrtf(var + 1e-5f);
    for (int d = 0; d < DD; ++d) {
        float v = S[d * GG + r];
        S[d * GG + r] = (v - mean) * rstd * g[d] + bl[d];
    }
}

__global__ __launch_bounds__(128) void k_headT(
    const float* __restrict__ seqT, const float* __restrict__ W1,
    const float* __restrict__ b1, const float* __restrict__ W2,
    const float* __restrict__ b2, float* __restrict__ out) {
    int b = blockIdx.x, t = threadIdx.x;
    __shared__ float pooled[DD];
    __shared__ float hid[64];
    const float4* row = (const float4*)(seqT + t * GG + b * TT);
    float4 s4 = make_float4(0.f, 0.f, 0.f, 0.f);
#pragma unroll
    for (int i = 0; i < 16; ++i) {
        float4 v = row[i];
        s4.x += v.x; s4.y += v.y; s4.z += v.z; s4.w += v.w;
    }
    pooled[t] = (s4.x + s4.y + s4.z + s4.w) * (1.f / TT);
    __syncthreads();
    if (t < 64) {
        float a = b1[t];
        const float* wr = W1 + t * DD;
        for (int k = 0; k < DD; ++k) a += pooled[k] * wr[k];
        hid[t] = fmaxf(a, 0.f);
    }
    __syncthreads();
    if (t < 2) {
        float a = b2[t];
        const float* wr = W2 + t * 64;
        for (int k = 0; k < 64; ++k) a += hid[k] * wr[k];
        out[b * 2 + t] = a;
    }
}

// ---------------- host ----------------

extern "C" void kernel_launch(void* const* d_in, const int* in_sizes, int n_in,
                              void* d_out, int out_size, void* d_ws, size_t ws_size,
                              hipStream_t stream) {
    const float* x     = (const float*)d_in[0];
    const int*   esrc  = (const int*)d_in[1];
    const int*   edst  = (const int*)d_in[2];
    const float* gW1   = (const float*)d_in[4];
    const float* gb1   = (const float*)d_in[5];
    const float* ln1g  = (const float*)d_in[6];
    const float* ln1b  = (const float*)d_in[7];
    const float* gW2   = (const float*)d_in[8];
    const float* gb2   = (const float*)d_in[9];
    const float* ln2g  = (const float*)d_in[10];
    const float* ln2b  = (const float*)d_in[11];
    const float* gW3   = (const float*)d_in[12];
    const float* gb3   = (const float*)d_in[13];
    const float* tWqkv = (const float*)d_in[14];
    const float* tbqkv = (const float*)d_in[15];
    const float* tWo   = (const float*)d_in[16];
    const float* tbo   = (const float*)d_in[17];
    const float* tg1   = (const float*)d_in[18];
    const float* tb1   = (const float*)d_in[19];
    const float* tg2   = (const float*)d_in[20];
    const float* tb2   = (const float*)d_in[21];
    const float* tWf1  = (const float*)d_in[22];
    const float* tbf1  = (const float*)d_in[23];
    const float* tWf2  = (const float*)d_in[24];
    const float* tbf2  = (const float*)d_in[25];
    const float* hW1   = (const float*)d_in[26];
    const float* hb1   = (const float*)d_in[27];
    const float* hW2   = (const float*)d_in[28];
    const float* hb2   = (const float*)d_in[29];
    float* out = (float*)d_out;

    int* cntN     = (int*)d_ws;              // NN
    int* gcnt     = cntN + NN;               // 512
    int* gbase    = gcnt + GG;               // 513 (pad 516)
    int* node_off = gbase + 516;             // NN+1 (pad NN+4)
    int* cursorN  = node_off + NN + 4;       // NN
    uint2* epackN = (uint2*)(cursorN + NN);  // EE
    float* bufA = (float*)(epackN + EE);     // NN*64
    float* bufB = bufA + (size_t)NN * 64;    // NN*64
    float* pooledT = bufB + (size_t)NN * 64; // 64*512
    float* seqT = pooledT + 64 * GG;         // 128*512
    float* qkvT = seqT + DD * GG;            // 384*512
    float* aT   = qkvT + 3 * DD * GG;        // 128*512
    float* f1T  = aT + DD * GG;              // 512*512

    const int BS = 256;
    const int NCHUNK = NN / CHK;  // 2048
    // CSR build
    hipMemsetAsync(cntN, 0, NN * sizeof(int), stream);
    hipMemsetAsync(pooledT, 0, 64 * GG * sizeof(float), stream);
    k_ncount<<<EE / BS, BS, 0, stream>>>(edst, cntN);
    k_gsum<<<GG, 64, 0, stream>>>(cntN, gcnt);
    k_gprefix<<<1, GG, 0, stream>>>(gcnt, gbase);
    k_nscan<<<GG, BS, 0, stream>>>(cntN, gbase, node_off, cursorN);
    k_escatter<<<EE / BS, BS, 0, stream>>>(esrc, edst, cntN, cursorN, epackN);

    // GCN: agg-then-transform, chunked grids
    k_gcn1<<<NCHUNK, BS, 0, stream>>>(x, gW1, gb1, ln1g, ln1b, cntN, node_off, epackN, bufA);
    k_agg<<<NCHUNK, BS, 0, stream>>>(bufA, cntN, node_off, epackN, bufB);
    k_lin_ln<<<NN / 64, BS, 0, stream>>>(bufB, gW2, gb2, ln2g, ln2b, bufA);
    k_agg_pool<<<NCHUNK, BS, 0, stream>>>(bufA, cntN, node_off, epackN, pooledT);
    k_emb<<<DD, GG, 0, stream>>>(pooledT, gW3, gb3, seqT);

    // Transformer (transposed activations)
    for (int l = 0; l < LL; l++) {
        k_gemmT<128, false, false><<<384, 128, 0, stream>>>(
            seqT, tWqkv + (size_t)l * 384 * 128, tbqkv + l * 384, nullptr, qkvT);
        k_attnT<<<BB * 4, TT, 0, stream>>>(qkvT, aT);
        k_gemmT<128, false, true><<<128, 128, 0, stream>>>(
            aT, tWo + (size_t)l * 128 * 128, tbo + l * 128, seqT, seqT);
        k_lnT<<<2, 256, 0, stream>>>(seqT, tg1 + l * 128, tb1 + l * 128);
        k_gemmT<128, true, false><<<512, 128, 0, stream>>>(
            seqT, tWf1 + (size_t)l * 512 * 128, tbf1 + l * 512, nullptr, f1T);
        k_gemmT<512, false, true><<<128, 128, 0, stream>>>(
            f1T, tWf2 + (size_t)l * 128 * 512, tbf2 + l * 128, seqT, seqT);
        k_lnT<<<2, 256, 0, stream>>>(seqT, tg2 + l * 128, tb2 + l * 128);
    }

    // head
    k_headT<<<BB, 128, 0, stream>>>(seqT, hW1, hb1, hW2, hb2, out);
}

// Round 7
// 709.359 us; speedup vs baseline: 1.0342x; 1.0342x over previous
//
#include <hip/hip_runtime.h>

#define NN   102400
#define EE   819200
#define GG   512
#define NPG  200
#define DD   128
#define TT   64
#define BB   8
#define LL   4

typedef unsigned int uint;

static __device__ __forceinline__ float wave_sum64(float v) {
#pragma unroll
    for (int off = 32; off > 0; off >>= 1) v += __shfl_xor(v, off, 64);
    return v;
}

// ---------------- CSR build (sort edges by dst node) ----------------

__global__ void k_ncount(const int* __restrict__ dst, int* __restrict__ cnt) {
    int e = blockIdx.x * blockDim.x + threadIdx.x;
    if (e < EE) atomicAdd(&cnt[dst[e]], 1);
}

__global__ __launch_bounds__(64) void k_gsum(const int* __restrict__ cnt,
                                             int* __restrict__ gcnt) {
    int g = blockIdx.x, t = threadIdx.x;
    int s = 0;
    for (int i = t; i < NPG; i += 64) s += cnt[g * NPG + i];
#pragma unroll
    for (int off = 32; off > 0; off >>= 1) s += __shfl_xor(s, off, 64);
    if (t == 0) gcnt[g] = s;
}

__global__ void k_gprefix(const int* __restrict__ gcnt, int* __restrict__ gbase) {
    __shared__ int sm[GG];
    int t = threadIdx.x;
    int c = gcnt[t];
    sm[t] = c;
    __syncthreads();
    for (int d = 1; d < GG; d <<= 1) {
        int v = (t >= d) ? sm[t - d] : 0;
        __syncthreads();
        sm[t] += v;
        __syncthreads();
    }
    gbase[t] = sm[t] - c;
    if (t == GG - 1) gbase[GG] = sm[t];
}

__global__ __launch_bounds__(256) void k_nscan(const int* __restrict__ cnt,
                                               const int* __restrict__ gbase,
                                               int* __restrict__ node_off,
                                               int* __restrict__ cursorN) {
    int g = blockIdx.x, t = threadIdx.x;
    __shared__ int sm[256];
    int c = (t < NPG) ? cnt[g * NPG + t] : 0;
    sm[t] = c;
    __syncthreads();
    for (int d = 1; d < 256; d <<= 1) {
        int v = (t >= d) ? sm[t - d] : 0;
        __syncthreads();
        sm[t] += v;
        __syncthreads();
    }
    if (t < NPG) {
        int off = gbase[g] + sm[t] - c;
        node_off[g * NPG + t] = off;
        cursorN[g * NPG + t] = off;
    }
    if (g == GG - 1 && t == 0) node_off[NN] = gbase[GG];
}

__global__ void k_escatter(const int* __restrict__ src, const int* __restrict__ dst,
                           const int* __restrict__ cnt, int* __restrict__ cursorN,
                           uint2* __restrict__ epackN) {
    int e = blockIdx.x * blockDim.x + threadIdx.x;
    if (e >= EE) return;
    int s = src[e], d = dst[e];
    int pos = atomicAdd(&cursorN[d], 1);
    float w = rsqrtf((float)(cnt[s] + 1)) * rsqrtf((float)(cnt[d] + 1));
    epackN[pos] = make_uint2((uint)s, __float_as_uint(w));  // GLOBAL src id
}

// ---------------- GCN: lane-parallel edge fetch ----------------

// layer 1: agg x (2-wide) + 2->64 transform + bias/relu/LN
__global__ __launch_bounds__(256) void k_gcn1(
    const float* __restrict__ x, const float* __restrict__ W1,
    const float* __restrict__ gb1, const float* __restrict__ lng,
    const float* __restrict__ lnb, const int* __restrict__ cnt,
    const int* __restrict__ node_off, const uint2* __restrict__ epackN,
    float* __restrict__ hout) {
    int n0 = blockIdx.x * 64;  // 1600 blocks
    __shared__ float2 axs[64];
    __shared__ int noff[65];
    __shared__ float dinvs[64];
    int tid = threadIdx.x, lane = tid & 63, wid = tid >> 6;
    if (tid <= 64) noff[tid] = node_off[n0 + tid];
    if (tid < 64) dinvs[tid] = 1.f / (float)(cnt[n0 + tid] + 1);
    __syncthreads();
    const float2* x2 = (const float2*)x;
    for (int i = wid; i < 64; i += 4) {
        int e0 = noff[i], E = noff[i + 1] - e0;
        float wx = 0.f, wy = 0.f;
        if (lane < E) {
            uint2 my = epackN[e0 + lane];   // coalesced, one shot
            float w = __uint_as_float(my.y);
            float2 xe = x2[my.x];
            wx = xe.x * w;
            wy = xe.y * w;
        }
        for (int e = 64; e < E; ++e) {      // rare tail
            uint2 ed = epackN[e0 + e];
            float w = __uint_as_float(ed.y);
            float2 xe = x2[ed.x];
            if (lane == 0) { wx += xe.x * w; wy += xe.y * w; }
        }
        wx = wave_sum64(wx);
        wy = wave_sum64(wy);
        if (lane == 0) {
            float2 xv = x2[n0 + i];
            axs[i] = make_float2(wx + xv.x * dinvs[i], wy + xv.y * dinvs[i]);
        }
    }
    __syncthreads();
    float w0 = W1[lane], w1 = W1[64 + lane];
    float gbj = gb1[lane], lgj = lng[lane], lbj = lnb[lane];
    for (int i = wid; i < 64; i += 4) {
        float2 a = axs[i];
        float u = fmaxf(a.x * w0 + a.y * w1 + gbj, 0.f);
        float mean = wave_sum64(u) * (1.f / 64.f);
        float dv = u - mean;
        float var = wave_sum64(dv * dv) * (1.f / 64.f);
        hout[(size_t)(n0 + i) * 64 + lane] = dv * rsqrtf(var + 1e-5f) * lgj + lbj;
    }
}

// fused: z = A_hat*t (agg into LDS) then h = LN(relu(z@W+b))
__global__ __launch_bounds__(256) void k_agg_lin_ln(
    const float* __restrict__ t, const float* __restrict__ W,
    const float* __restrict__ gb, const float* __restrict__ lng,
    const float* __restrict__ lnb, const int* __restrict__ cnt,
    const int* __restrict__ node_off, const uint2* __restrict__ epackN,
    float* __restrict__ hout) {
    int n0 = blockIdx.x * 64;  // 1600 blocks
    __shared__ float hs[64][64];
    __shared__ float wsm[64 * 64];
    __shared__ int noff[65];
    __shared__ float dinvs[64];
    int tid = threadIdx.x, lane = tid & 63, wid = tid >> 6;
    if (tid <= 64) noff[tid] = node_off[n0 + tid];
    if (tid < 64) dinvs[tid] = 1.f / (float)(cnt[n0 + tid] + 1);
    for (int i = tid; i < 1024; i += 256) ((float4*)wsm)[i] = ((const float4*)W)[i];
    __syncthreads();
    for (int i = wid; i < 64; i += 4) {
        int e0 = noff[i], E = noff[i + 1] - e0;
        uint2 my = make_uint2(0u, 0u);
        if (lane < E) my = epackN[e0 + lane];
        float acc = t[(size_t)(n0 + i) * 64 + lane] * dinvs[i];
        int El = E < 64 ? E : 64;
        for (int e = 0; e < El; ++e) {
            int s = __shfl((int)my.x, e);
            float w = __shfl(__uint_as_float(my.y), e);
            acc += t[(size_t)s * 64 + lane] * w;
        }
        for (int e = 64; e < E; ++e) {
            uint2 ed = epackN[e0 + e];
            acc += t[(size_t)ed.x * 64 + lane] * __uint_as_float(ed.y);
        }
        hs[i][lane] = acc;
    }
    __syncthreads();
    float wreg[64];
#pragma unroll
    for (int k = 0; k < 64; ++k) wreg[k] = wsm[k * 64 + lane];
    float gbj = gb[lane], lgj = lng[lane], lbj = lnb[lane];
    for (int i = wid; i < 64; i += 4) {
        const float4* hrow = (const float4*)&hs[i][0];
        float a0 = 0.f, a1 = 0.f;
#pragma unroll
        for (int k4 = 0; k4 < 16; k4 += 2) {
            float4 h0 = hrow[k4], h1 = hrow[k4 + 1];
            a0 += h0.x * wreg[4 * k4] + h0.y * wreg[4 * k4 + 1] +
                  h0.z * wreg[4 * k4 + 2] + h0.w * wreg[4 * k4 + 3];
            a1 += h1.x * wreg[4 * k4 + 4] + h1.y * wreg[4 * k4 + 5] +
                  h1.z * wreg[4 * k4 + 6] + h1.w * wreg[4 * k4 + 7];
        }
        float u = fmaxf(a0 + a1 + gbj, 0.f);
        float mean = wave_sum64(u) * (1.f / 64.f);
        float dv = u - mean;
        float var = wave_sum64(dv * dv) * (1.f / 64.f);
        hout[(size_t)(n0 + i) * 64 + lane] = dv * rsqrtf(var + 1e-5f) * lgj + lbj;
    }
}

// layer-3 aggregation + partial mean pooling (atomic into zeroed pooledT)
__global__ __launch_bounds__(256) void k_agg_pool(
    const float* __restrict__ t, const int* __restrict__ cnt,
    const int* __restrict__ node_off, const uint2* __restrict__ epackN,
    float* __restrict__ pooledT) {
    int c = blockIdx.x;        // 2048 chunks of 50 (graph-aligned)
    int g = c >> 2;
    int n0 = c * 50;
    __shared__ int noff[51];
    __shared__ float dinvs[50];
    __shared__ float red[4][64];
    int tid = threadIdx.x, lane = tid & 63, wid = tid >> 6;
    if (tid <= 50) noff[tid] = node_off[n0 + tid];
    if (tid < 50) dinvs[tid] = 1.f / (float)(cnt[n0 + tid] + 1);
    __syncthreads();
    float rsum = 0.f;
    for (int i = wid; i < 50; i += 4) {
        int e0 = noff[i], E = noff[i + 1] - e0;
        uint2 my = make_uint2(0u, 0u);
        if (lane < E) my = epackN[e0 + lane];
        float acc = t[(size_t)(n0 + i) * 64 + lane] * dinvs[i];
        int El = E < 64 ? E : 64;
        for (int e = 0; e < El; ++e) {
            int s = __shfl((int)my.x, e);
            float w = __shfl(__uint_as_float(my.y), e);
            acc += t[(size_t)s * 64 + lane] * w;
        }
        for (int e = 64; e < E; ++e) {
            uint2 ed = epackN[e0 + e];
            acc += t[(size_t)ed.x * 64 + lane] * __uint_as_float(ed.y);
        }
        rsum += acc;
    }
    red[wid][lane] = rsum;
    __syncthreads();
    if (tid < 64)
        atomicAdd(&pooledT[tid * GG + g],
                  (red[0][tid] + red[1][tid] + red[2][tid] + red[3][tid]) * (1.f / NPG));
}

// pooled(64) @ W3 -> 128 + b3 + PE -> seq[g][d] row-major
__global__ __launch_bounds__(128) void k_emb(
    const float* __restrict__ pooledT, const float* __restrict__ W3,
    const float* __restrict__ b3, float* __restrict__ seq) {
    int g = blockIdx.x, d = threadIdx.x;
    float acc = b3[d];
#pragma unroll 8
    for (int k = 0; k < 64; ++k) acc += pooledT[k * GG + g] * W3[k * DD + d];
    float freq = expf((float)(d & ~1) * (-9.210340371976184f / 128.f));
    float ang = (float)(g & (TT - 1)) * freq;
    acc += (d & 1) ? cosf(ang) : sinf(ang);
    seq[(size_t)g * DD + d] = acc;
}

// ---------------- Transformer (row-major, tiled GEMMs, fused LN) ----------------

// C[M][N] = A[M][K] @ W[N][K]^T + bias ; optional relu; optional (+res, LN) when BN==N==128
template <int BM, int BN, int BK, int K, bool RELU, bool RESLN>
__global__ __launch_bounds__(256) void k_gemm(
    const float* __restrict__ A, const float* __restrict__ W,
    const float* __restrict__ bias, const float* __restrict__ res,
    const float* __restrict__ lng, const float* __restrict__ lnb,
    float* __restrict__ C, int N) {
    constexpr int TX = BN / 4;
    constexpr int TY = 256 / TX;
    __shared__ float as[BK][BM + 4];
    __shared__ float ws[BK][BN + 4];
    __shared__ float smc[RESLN ? BM * (BN + 4) : 4];
    int tid = threadIdx.x;
    int r0 = blockIdx.y * BM, c0 = blockIdx.x * BN;
    int tx = tid % TX, ty = tid / TX;
    float acc[4][4] = {};
    for (int k0 = 0; k0 < K; k0 += BK) {
        for (int li = tid; li < BM * BK / 4; li += 256) {
            int r = li / (BK / 4), kq = li % (BK / 4);
            float4 v = *(const float4*)&A[(size_t)(r0 + r) * K + k0 + kq * 4];
            as[kq * 4 + 0][r] = v.x; as[kq * 4 + 1][r] = v.y;
            as[kq * 4 + 2][r] = v.z; as[kq * 4 + 3][r] = v.w;
        }
        for (int li = tid; li < BN * BK / 4; li += 256) {
            int cc = li / (BK / 4), kq = li % (BK / 4);
            float4 v = *(const float4*)&W[(size_t)(c0 + cc) * K + k0 + kq * 4];
            ws[kq * 4 + 0][cc] = v.x; ws[kq * 4 + 1][cc] = v.y;
            ws[kq * 4 + 2][cc] = v.z; ws[kq * 4 + 3][cc] = v.w;
        }
        __syncthreads();
#pragma unroll
        for (int k = 0; k < BK; ++k) {
            float4 av = *(const float4*)&as[k][ty * 4];
            float4 wv = *(const float4*)&ws[k][tx * 4];
            float a4[4] = {av.x, av.y, av.z, av.w};
            float w4[4] = {wv.x, wv.y, wv.z, wv.w};
#pragma unroll
            for (int i = 0; i < 4; ++i)
#pragma unroll
                for (int j = 0; j < 4; ++j) acc[i][j] += a4[i] * w4[j];
        }
        __syncthreads();
    }
    float4 bv = *(const float4*)&bias[c0 + tx * 4];
    float b4[4] = {bv.x, bv.y, bv.z, bv.w};
    if constexpr (!RESLN) {
#pragma unroll
        for (int i = 0; i < 4; ++i) {
            float4 o;
            o.x = acc[i][0] + b4[0]; o.y = acc[i][1] + b4[1];
            o.z = acc[i][2] + b4[2]; o.w = acc[i][3] + b4[3];
            if (RELU) {
                o.x = fmaxf(o.x, 0.f); o.y = fmaxf(o.y, 0.f);
                o.z = fmaxf(o.z, 0.f); o.w = fmaxf(o.w, 0.f);
            }
            *(float4*)&C[(size_t)(r0 + ty * 4 + i) * N + c0 + tx * 4] = o;
        }
    } else {
        float(*sm)[BN + 4] = (float(*)[BN + 4])smc;
#pragma unroll
        for (int i = 0; i < 4; ++i) {
            float4 r4 = *(const float4*)&res[(size_t)(r0 + ty * 4 + i) * N + tx * 4];
            sm[ty * 4 + i][tx * 4 + 0] = acc[i][0] + b4[0] + r4.x;
            sm[ty * 4 + i][tx * 4 + 1] = acc[i][1] + b4[1] + r4.y;
            sm[ty * 4 + i][tx * 4 + 2] = acc[i][2] + b4[2] + r4.z;
            sm[ty * 4 + i][tx * 4 + 3] = acc[i][3] + b4[3] + r4.w;
        }
        __syncthreads();
        int wv_ = tid >> 6, ln = tid & 63;
        for (int r = wv_ * (BM / 4); r < (wv_ + 1) * (BM / 4); ++r) {
            float v0 = sm[r][ln], v1 = sm[r][ln + 64];
            float mean = wave_sum64(v0 + v1) * (1.f / 128.f);
            float d0 = v0 - mean, d1 = v1 - mean;
            float var = wave_sum64(d0 * d0 + d1 * d1) * (1.f / 128.f);
            float rstd = rsqrtf(var + 1e-5f);
            C[(size_t)(r0 + r) * N + ln] = d0 * rstd * lng[ln] + lnb[ln];
            C[(size_t)(r0 + r) * N + ln + 64] = d1 * rstd * lng[ln + 64] + lnb[ln + 64];
        }
    }
}

// attention: block per (b,h), 256 threads
__global__ __launch_bounds__(256) void k_attn(const float* __restrict__ qkv,
                                              float* __restrict__ abuf) {
    int b = blockIdx.x >> 2, h = blockIdx.x & 3;
    __shared__ float Qs[64][36], Ks[64][36], Vs[64][36];
    __shared__ float Ss[64][68];
    int tid = threadIdx.x;
    const float* base = qkv + (size_t)(b * 64) * 384 + h * 32;
    for (int li = tid; li < 512; li += 256) {
        int r = li >> 3, dq = li & 7;
        *(float4*)&Qs[r][dq * 4] = *(const float4*)&base[(size_t)r * 384 + dq * 4];
        *(float4*)&Ks[r][dq * 4] = *(const float4*)&base[(size_t)r * 384 + 128 + dq * 4];
        *(float4*)&Vs[r][dq * 4] = *(const float4*)&base[(size_t)r * 384 + 256 + dq * 4];
    }
    __syncthreads();
    int q = tid >> 2, kg = tid & 3;
    const float scale = 0.17677669529663687f;  // 1/sqrt(32)
    float p[16];
    float mx = -1e30f;
#pragma unroll
    for (int kk = 0; kk < 16; ++kk) {
        int k = kg * 16 + kk;
        float a = 0.f;
#pragma unroll
        for (int dq = 0; dq < 8; ++dq) {
            float4 qv = *(const float4*)&Qs[q][dq * 4];
            float4 kv = *(const float4*)&Ks[k][dq * 4];
            a += qv.x * kv.x + qv.y * kv.y + qv.z * kv.z + qv.w * kv.w;
        }
        p[kk] = a * scale;
        mx = fmaxf(mx, p[kk]);
    }
    mx = fmaxf(mx, __shfl_xor(mx, 1));
    mx = fmaxf(mx, __shfl_xor(mx, 2));
    float ssum = 0.f;
#pragma unroll
    for (int kk = 0; kk < 16; ++kk) {
        p[kk] = expf(p[kk] - mx);
        ssum += p[kk];
    }
    ssum += __shfl_xor(ssum, 1);
    ssum += __shfl_xor(ssum, 2);
    float inv = 1.f / ssum;
#pragma unroll
    for (int kk = 0; kk < 16; ++kk) Ss[q][kg * 16 + kk] = p[kk] * inv;
    __syncthreads();
    int dg = kg;
    float o[8] = {};
    for (int k = 0; k < 64; ++k) {
        float pw = Ss[q][k];
        float4 v0 = *(const float4*)&Vs[k][dg * 8];
        float4 v1 = *(const float4*)&Vs[k][dg * 8 + 4];
        o[0] += pw * v0.x; o[1] += pw * v0.y; o[2] += pw * v0.z; o[3] += pw * v0.w;
        o[4] += pw * v1.x; o[5] += pw * v1.y; o[6] += pw * v1.z; o[7] += pw * v1.w;
    }
    float* op = abuf + (size_t)(b * 64 + q) * DD + h * 32 + dg * 8;
    *(float4*)&op[0] = make_float4(o[0], o[1], o[2], o[3]);
    *(float4*)&op[4] = make_float4(o[4], o[5], o[6], o[7]);
}

__global__ __launch_bounds__(128) void k_head(
    const float* __restrict__ seq, const float* __restrict__ W1,
    const float* __restrict__ b1, const float* __restrict__ W2,
    const float* __restrict__ b2, float* __restrict__ out) {
    int b = blockIdx.x, t = threadIdx.x;
    __shared__ float pooled[DD];
    __shared__ float hid[64];
    float s = 0.f;
    for (int i = 0; i < TT; ++i) s += seq[(size_t)(b * TT + i) * DD + t];
    pooled[t] = s * (1.f / TT);
    __syncthreads();
    if (t < 64) {
        float a = b1[t];
        const float* wr = W1 + t * DD;
        for (int k = 0; k < DD; ++k) a += pooled[k] * wr[k];
        hid[t] = fmaxf(a, 0.f);
    }
    __syncthreads();
    if (t < 2) {
        float a = b2[t];
        const float* wr = W2 + t * 64;
        for (int k = 0; k < 64; ++k) a += hid[k] * wr[k];
        out[b * 2 + t] = a;
    }
}

// ---------------- host ----------------

extern "C" void kernel_launch(void* const* d_in, const int* in_sizes, int n_in,
                              void* d_out, int out_size, void* d_ws, size_t ws_size,
                              hipStream_t stream) {
    const float* x     = (const float*)d_in[0];
    const int*   esrc  = (const int*)d_in[1];
    const int*   edst  = (const int*)d_in[2];
    const float* gW1   = (const float*)d_in[4];
    const float* gb1   = (const float*)d_in[5];
    const float* ln1g  = (const float*)d_in[6];
    const float* ln1b  = (const float*)d_in[7];
    const float* gW2   = (const float*)d_in[8];
    const float* gb2   = (const float*)d_in[9];
    const float* ln2g  = (const float*)d_in[10];
    const float* ln2b  = (const float*)d_in[11];
    const float* gW3   = (const float*)d_in[12];
    const float* gb3   = (const float*)d_in[13];
    const float* tWqkv = (const float*)d_in[14];
    const float* tbqkv = (const float*)d_in[15];
    const float* tWo   = (const float*)d_in[16];
    const float* tbo   = (const float*)d_in[17];
    const float* tg1   = (const float*)d_in[18];
    const float* tb1   = (const float*)d_in[19];
    const float* tg2   = (const float*)d_in[20];
    const float* tb2   = (const float*)d_in[21];
    const float* tWf1  = (const float*)d_in[22];
    const float* tbf1  = (const float*)d_in[23];
    const float* tWf2  = (const float*)d_in[24];
    const float* tbf2  = (const float*)d_in[25];
    const float* hW1   = (const float*)d_in[26];
    const float* hb1   = (const float*)d_in[27];
    const float* hW2   = (const float*)d_in[28];
    const float* hb2   = (const float*)d_in[29];
    float* out = (float*)d_out;

    int* cntN     = (int*)d_ws;              // NN
    int* gcnt     = cntN + NN;               // 512
    int* gbase    = gcnt + GG;               // 513 (pad 516)
    int* node_off = gbase + 516;             // NN+1 (pad NN+4)
    int* cursorN  = node_off + NN + 4;       // NN
    uint2* epackN = (uint2*)(cursorN + NN);  // EE
    float* bufA = (float*)(epackN + EE);     // NN*64
    float* bufB = bufA + (size_t)NN * 64;    // NN*64
    float* pooledT = bufB + (size_t)NN * 64; // 64*512
    float* seq  = pooledT + 64 * GG;         // 512*128
    float* qkvb = seq + GG * DD;             // 512*384
    float* abuf = qkvb + GG * 384;           // 512*128
    float* f1b  = abuf + GG * DD;            // 512*512

    const int BS = 256;
    // CSR build
    hipMemsetAsync(cntN, 0, NN * sizeof(int), stream);
    hipMemsetAsync(pooledT, 0, 64 * GG * sizeof(float), stream);
    k_ncount<<<EE / BS, BS, 0, stream>>>(edst, cntN);
    k_gsum<<<GG, 64, 0, stream>>>(cntN, gcnt);
    k_gprefix<<<1, GG, 0, stream>>>(gcnt, gbase);
    k_nscan<<<GG, BS, 0, stream>>>(cntN, gbase, node_off, cursorN);
    k_escatter<<<EE / BS, BS, 0, stream>>>(esrc, edst, cntN, cursorN, epackN);

    // GCN
    k_gcn1<<<NN / 64, BS, 0, stream>>>(x, gW1, gb1, ln1g, ln1b, cntN, node_off, epackN, bufA);
    k_agg_lin_ln<<<NN / 64, BS, 0, stream>>>(bufA, gW2, gb2, ln2g, ln2b, cntN, node_off,
                                             epackN, bufB);
    k_agg_pool<<<NN / 50, BS, 0, stream>>>(bufB, cntN, node_off, epackN, pooledT);
    k_emb<<<GG, DD, 0, stream>>>(pooledT, gW3, gb3, seq);

    // Transformer (row-major)
    for (int l = 0; l < LL; l++) {
        k_gemm<64, 64, 32, 128, false, false><<<dim3(6, 8), 256, 0, stream>>>(
            seq, tWqkv + (size_t)l * 384 * 128, tbqkv + l * 384,
            nullptr, nullptr, nullptr, qkvb, 384);
        k_attn<<<BB * 4, 256, 0, stream>>>(qkvb, abuf);
        k_gemm<32, 128, 32, 128, false, true><<<dim3(1, 16), 256, 0, stream>>>(
            abuf, tWo + (size_t)l * 128 * 128, tbo + l * 128,
            seq, tg1 + l * 128, tb1 + l * 128, seq, 128);
        k_gemm<64, 64, 32, 128, true, false><<<dim3(8, 8), 256, 0, stream>>>(
            seq, tWf1 + (size_t)l * 512 * 128, tbf1 + l * 512,
            nullptr, nullptr, nullptr, f1b, 512);
        k_gemm<32, 128, 32, 512, false, true><<<dim3(1, 16), 256, 0, stream>>>(
            f1b, tWf2 + (size_t)l * 128 * 512, tbf2 + l * 128,
            seq, tg2 + l * 128, tb2 + l * 128, seq, 128);
    }

    // head
    k_head<<<BB, DD, 0, stream>>>(seq, hW1, hb1, hW2, hb2, out);
}

// Round 8
// 613.668 us; speedup vs baseline: 1.1954x; 1.1559x over previous
//
#include <hip/hip_runtime.h>

#define NN   102400
#define EE   819200
#define GG   512
#define NPG  200
#define DD   128
#define TT   64
#define BB   8
#define LL   4

typedef unsigned int uint;

static __device__ __forceinline__ float wave_sum64(float v) {
#pragma unroll
    for (int off = 32; off > 0; off >>= 1) v += __shfl_xor(v, off, 64);
    return v;
}

// two independent butterfly chains (half the exposed latency of two sequential)
static __device__ __forceinline__ void wave_sum64_2(float& a, float& b) {
#pragma unroll
    for (int off = 32; off > 0; off >>= 1) {
        a += __shfl_xor(a, off, 64);
        b += __shfl_xor(b, off, 64);
    }
}

// ---------------- CSR build (sort edges by dst node) ----------------

__global__ void k_ncount(const int* __restrict__ dst, int* __restrict__ cnt) {
    int e = blockIdx.x * blockDim.x + threadIdx.x;
    if (e < EE) atomicAdd(&cnt[dst[e]], 1);
}

__global__ __launch_bounds__(64) void k_gsum(const int* __restrict__ cnt,
                                             int* __restrict__ gcnt) {
    int g = blockIdx.x, t = threadIdx.x;
    int s = 0;
    for (int i = t; i < NPG; i += 64) s += cnt[g * NPG + i];
#pragma unroll
    for (int off = 32; off > 0; off >>= 1) s += __shfl_xor(s, off, 64);
    if (t == 0) gcnt[g] = s;
}

__global__ void k_gprefix(const int* __restrict__ gcnt, int* __restrict__ gbase) {
    __shared__ int sm[GG];
    int t = threadIdx.x;
    int c = gcnt[t];
    sm[t] = c;
    __syncthreads();
    for (int d = 1; d < GG; d <<= 1) {
        int v = (t >= d) ? sm[t - d] : 0;
        __syncthreads();
        sm[t] += v;
        __syncthreads();
    }
    gbase[t] = sm[t] - c;
    if (t == GG - 1) gbase[GG] = sm[t];
}

__global__ __launch_bounds__(256) void k_nscan(const int* __restrict__ cnt,
                                               const int* __restrict__ gbase,
                                               int* __restrict__ node_off,
                                               int* __restrict__ cursorN) {
    int g = blockIdx.x, t = threadIdx.x;
    __shared__ int sm[256];
    int c = (t < NPG) ? cnt[g * NPG + t] : 0;
    sm[t] = c;
    __syncthreads();
    for (int d = 1; d < 256; d <<= 1) {
        int v = (t >= d) ? sm[t - d] : 0;
        __syncthreads();
        sm[t] += v;
        __syncthreads();
    }
    if (t < NPG) {
        int off = gbase[g] + sm[t] - c;
        node_off[g * NPG + t] = off;
        cursorN[g * NPG + t] = off;
    }
    if (g == GG - 1 && t == 0) node_off[NN] = gbase[GG];
}

// also accumulates column sums of A_hat (cw[src] += w) for the pooled-readout algebra
__global__ void k_escatter(const int* __restrict__ src, const int* __restrict__ dst,
                           const int* __restrict__ cnt, int* __restrict__ cursorN,
                           uint2* __restrict__ epackN, float* __restrict__ cw) {
    int e = blockIdx.x * blockDim.x + threadIdx.x;
    if (e >= EE) return;
    int s = src[e], d = dst[e];
    int pos = atomicAdd(&cursorN[d], 1);
    float w = rsqrtf((float)(cnt[s] + 1)) * rsqrtf((float)(cnt[d] + 1));
    epackN[pos] = make_uint2((uint)s, __float_as_uint(w));
    atomicAdd(&cw[s], w);
}

// ---------------- GCN ----------------
// XCD-aware swizzle: 2048 chunks of 50 nodes; XCD x gets graphs [64x, 64x+64)

// layer 1: agg x (2-wide) + 2->64 transform + bias/relu/LN, all in-registers
__global__ __launch_bounds__(256) void k_gcn1(
    const float* __restrict__ x, const float* __restrict__ W1,
    const float* __restrict__ gb1, const float* __restrict__ lng,
    const float* __restrict__ lnb, const int* __restrict__ cnt,
    const int* __restrict__ node_off, const uint2* __restrict__ epackN,
    float* __restrict__ hout) {
    int c = ((blockIdx.x & 7) << 8) | (blockIdx.x >> 3);
    int n0 = c * 50;
    __shared__ int noff[51];
    __shared__ float dinvs[50];
    int tid = threadIdx.x, lane = tid & 63, wid = tid >> 6;
    if (tid <= 50) noff[tid] = node_off[n0 + tid];
    if (tid < 50) dinvs[tid] = 1.f / (float)(cnt[n0 + tid] + 1);
    __syncthreads();
    const float2* x2 = (const float2*)x;
    float w0 = W1[lane], w1 = W1[64 + lane];
    float gbj = gb1[lane], lgj = lng[lane], lbj = lnb[lane];
    for (int i = wid; i < 50; i += 4) {
        int e0 = noff[i], E = noff[i + 1] - e0;
        float wx = 0.f, wy = 0.f;
        if (lane < E) {
            uint2 my = epackN[e0 + lane];
            float w = __uint_as_float(my.y);
            float2 xe = x2[my.x];
            wx = xe.x * w;
            wy = xe.y * w;
        }
        for (int e = 64; e < E; ++e) {  // rare tail
            uint2 ed = epackN[e0 + e];
            if (lane == 0) {
                float w = __uint_as_float(ed.y);
                float2 xe = x2[ed.x];
                wx += xe.x * w;
                wy += xe.y * w;
            }
        }
        wave_sum64_2(wx, wy);
        float2 xv = x2[n0 + i];
        wx += xv.x * dinvs[i];
        wy += xv.y * dinvs[i];
        float u = fmaxf(wx * w0 + wy * w1 + gbj, 0.f);
        float s = u, q = u * u;
        wave_sum64_2(s, q);
        float mean = s * (1.f / 64.f);
        float var = q * (1.f / 64.f) - mean * mean;
        hout[(size_t)(n0 + i) * 64 + lane] = (u - mean) * rsqrtf(var + 1e-5f) * lgj + lbj;
    }
}

// fused layer 2: z = A_hat*t (gather), h = LN(relu(z@W2+b2))
__global__ __launch_bounds__(256) void k_agg_lin_ln(
    const float* __restrict__ t, const float* __restrict__ W,
    const float* __restrict__ gb, const float* __restrict__ lng,
    const float* __restrict__ lnb, const int* __restrict__ cnt,
    const int* __restrict__ node_off, const uint2* __restrict__ epackN,
    float* __restrict__ hout) {
    int c = ((blockIdx.x & 7) << 8) | (blockIdx.x >> 3);
    int n0 = c * 50;
    __shared__ float hs[50][64];
    __shared__ float wsm[64 * 64];
    __shared__ int noff[51];
    __shared__ float dinvs[50];
    int tid = threadIdx.x, lane = tid & 63, wid = tid >> 6;
    if (tid <= 50) noff[tid] = node_off[n0 + tid];
    if (tid < 50) dinvs[tid] = 1.f / (float)(cnt[n0 + tid] + 1);
    for (int i = tid; i < 1024; i += 256) ((float4*)wsm)[i] = ((const float4*)W)[i];
    __syncthreads();
    for (int i = wid; i < 50; i += 4) {
        int e0 = noff[i], E = noff[i + 1] - e0;
        uint2 my = make_uint2(0u, 0u);
        if (lane < E) my = epackN[e0 + lane];
        float acc = t[(size_t)(n0 + i) * 64 + lane] * dinvs[i];
        int El = E < 64 ? E : 64;
        for (int e = 0; e < El; ++e) {
            int s = __shfl((int)my.x, e);
            float w = __shfl(__uint_as_float(my.y), e);
            acc += t[(size_t)s * 64 + lane] * w;
        }
        for (int e = 64; e < E; ++e) {
            uint2 ed = epackN[e0 + e];
            acc += t[(size_t)ed.x * 64 + lane] * __uint_as_float(ed.y);
        }
        hs[i][lane] = acc;
    }
    __syncthreads();
    float wreg[64];
#pragma unroll
    for (int k = 0; k < 64; ++k) wreg[k] = wsm[k * 64 + lane];
    float gbj = gb[lane], lgj = lng[lane], lbj = lnb[lane];
    for (int i = wid; i < 50; i += 4) {
        const float4* hrow = (const float4*)&hs[i][0];
        float a0 = 0.f, a1 = 0.f;
#pragma unroll
        for (int k4 = 0; k4 < 16; k4 += 2) {
            float4 h0 = hrow[k4], h1 = hrow[k4 + 1];
            a0 += h0.x * wreg[4 * k4] + h0.y * wreg[4 * k4 + 1] +
                  h0.z * wreg[4 * k4 + 2] + h0.w * wreg[4 * k4 + 3];
            a1 += h1.x * wreg[4 * k4 + 4] + h1.y * wreg[4 * k4 + 5] +
                  h1.z * wreg[4 * k4 + 6] + h1.w * wreg[4 * k4 + 7];
        }
        float u = fmaxf(a0 + a1 + gbj, 0.f);
        float s = u, q = u * u;
        wave_sum64_2(s, q);
        float mean = s * (1.f / 64.f);
        float var = q * (1.f / 64.f) - mean * mean;
        hout[(size_t)(n0 + i) * 64 + lane] = (u - mean) * rsqrtf(var + 1e-5f) * lgj + lbj;
    }
}

// layer 3 + readout collapsed: pooled_g = (1/200) sum_j (1/deg_j + cw_j) * h2_j
__global__ __launch_bounds__(256) void k_wpool(
    const float* __restrict__ h2, const float* __restrict__ cw,
    const int* __restrict__ cnt, float* __restrict__ pooled) {
    int g = ((blockIdx.x & 7) << 6) | (blockIdx.x >> 3);
    int n0 = g * NPG;
    __shared__ float wgt[NPG];
    __shared__ float red[4][64];
    int tid = threadIdx.x, lane = tid & 63, wid = tid >> 6;
    for (int i = tid; i < NPG; i += 256)
        wgt[i] = cw[n0 + i] + 1.f / (float)(cnt[n0 + i] + 1);
    __syncthreads();
    float acc = 0.f;
    for (int i = wid; i < NPG; i += 4)
        acc += h2[(size_t)(n0 + i) * 64 + lane] * wgt[i];
    red[wid][lane] = acc;
    __syncthreads();
    if (tid < 64)
        pooled[g * 64 + tid] =
            (red[0][tid] + red[1][tid] + red[2][tid] + red[3][tid]) * (1.f / NPG);
}

// pooled(64) @ W3 -> 128 + b3 + PE -> seq[g][d]
__global__ __launch_bounds__(128) void k_emb(
    const float* __restrict__ pooled, const float* __restrict__ W3,
    const float* __restrict__ b3, float* __restrict__ seq) {
    int g = blockIdx.x, d = threadIdx.x;
    __shared__ float ps[64];
    if (d < 64) ps[d] = pooled[g * 64 + d];
    __syncthreads();
    float acc = b3[d];
#pragma unroll 8
    for (int k = 0; k < 64; ++k) acc += ps[k] * W3[k * DD + d];
    float freq = expf((float)(d & ~1) * (-9.210340371976184f / 128.f));
    float ang = (float)(g & (TT - 1)) * freq;
    acc += (d & 1) ? cosf(ang) : sinf(ang);
    seq[(size_t)g * DD + d] = acc;
}

// ---------------- Transformer (row-major, tiled GEMMs, fused LN) ----------------

template <int BM, int BN, int BK, int K, bool RELU, bool RESLN>
__global__ __launch_bounds__(256) void k_gemm(
    const float* __restrict__ A, const float* __restrict__ W,
    const float* __restrict__ bias, const float* __restrict__ res,
    const float* __restrict__ lng, const float* __restrict__ lnb,
    float* __restrict__ C, int N) {
    constexpr int TX = BN / 4;
    constexpr int TY = 256 / TX;
    constexpr int MR = BM / TY;      // rows per thread
    __shared__ float as[BK][BM + 4];
    __shared__ float ws[BK][BN + 4];
    __shared__ float smc[RESLN ? BM * (BN + 4) : 4];
    int tid = threadIdx.x;
    int r0 = blockIdx.y * BM, c0 = blockIdx.x * BN;
    int tx = tid % TX, ty = tid / TX;
    float acc[MR][4] = {};
    for (int k0 = 0; k0 < K; k0 += BK) {
        for (int li = tid; li < BM * BK / 4; li += 256) {
            int r = li / (BK / 4), kq = li % (BK / 4);
            float4 v = *(const float4*)&A[(size_t)(r0 + r) * K + k0 + kq * 4];
            as[kq * 4 + 0][r] = v.x; as[kq * 4 + 1][r] = v.y;
            as[kq * 4 + 2][r] = v.z; as[kq * 4 + 3][r] = v.w;
        }
        for (int li = tid; li < BN * BK / 4; li += 256) {
            int cc = li / (BK / 4), kq = li % (BK / 4);
            float4 v = *(const float4*)&W[(size_t)(c0 + cc) * K + k0 + kq * 4];
            ws[kq * 4 + 0][cc] = v.x; ws[kq * 4 + 1][cc] = v.y;
            ws[kq * 4 + 2][cc] = v.z; ws[kq * 4 + 3][cc] = v.w;
        }
        __syncthreads();
#pragma unroll
        for (int k = 0; k < BK; ++k) {
            float4 wv = *(const float4*)&ws[k][tx * 4];
            float w4[4] = {wv.x, wv.y, wv.z, wv.w};
#pragma unroll
            for (int i = 0; i < MR; ++i) {
                float a = as[k][ty * MR + i];
#pragma unroll
                for (int j = 0; j < 4; ++j) acc[i][j] += a * w4[j];
            }
        }
        __syncthreads();
    }
    float4 bv = *(const float4*)&bias[c0 + tx * 4];
    float b4[4] = {bv.x, bv.y, bv.z, bv.w};
    if constexpr (!RESLN) {
#pragma unroll
        for (int i = 0; i < MR; ++i) {
            float4 o;
            o.x = acc[i][0] + b4[0]; o.y = acc[i][1] + b4[1];
            o.z = acc[i][2] + b4[2]; o.w = acc[i][3] + b4[3];
            if (RELU) {
                o.x = fmaxf(o.x, 0.f); o.y = fmaxf(o.y, 0.f);
                o.z = fmaxf(o.z, 0.f); o.w = fmaxf(o.w, 0.f);
            }
            *(float4*)&C[(size_t)(r0 + ty * MR + i) * N + c0 + tx * 4] = o;
        }
    } else {
        float(*sm)[BN + 4] = (float(*)[BN + 4])smc;
#pragma unroll
        for (int i = 0; i < MR; ++i) {
            float4 r4 = *(const float4*)&res[(size_t)(r0 + ty * MR + i) * N + tx * 4];
            sm[ty * MR + i][tx * 4 + 0] = acc[i][0] + b4[0] + r4.x;
            sm[ty * MR + i][tx * 4 + 1] = acc[i][1] + b4[1] + r4.y;
            sm[ty * MR + i][tx * 4 + 2] = acc[i][2] + b4[2] + r4.z;
            sm[ty * MR + i][tx * 4 + 3] = acc[i][3] + b4[3] + r4.w;
        }
        __syncthreads();
        int wv_ = tid >> 6, ln = tid & 63;
        for (int r = wv_ * (BM / 4); r < (wv_ + 1) * (BM / 4); ++r) {
            float v0 = sm[r][ln], v1 = sm[r][ln + 64];
            float s = v0 + v1, q = v0 * v0 + v1 * v1;
            wave_sum64_2(s, q);
            float mean = s * (1.f / 128.f);
            float var = q * (1.f / 128.f) - mean * mean;
            float rstd = rsqrtf(var + 1e-5f);
            C[(size_t)(r0 + r) * N + ln] = (v0 - mean) * rstd * lng[ln] + lnb[ln];
            C[(size_t)(r0 + r) * N + ln + 64] =
                (v1 - mean) * rstd * lng[ln + 64] + lnb[ln + 64];
        }
    }
}

// attention: block per (b,h), 256 threads
__global__ __launch_bounds__(256) void k_attn(const float* __restrict__ qkv,
                                              float* __restrict__ abuf) {
    int b = blockIdx.x >> 2, h = blockIdx.x & 3;
    __shared__ float Qs[64][36], Ks[64][36], Vs[64][36];
    __shared__ float Ss[64][68];
    int tid = threadIdx.x;
    const float* base = qkv + (size_t)(b * 64) * 384 + h * 32;
    for (int li = tid; li < 512; li += 256) {
        int r = li >> 3, dq = li & 7;
        *(float4*)&Qs[r][dq * 4] = *(const float4*)&base[(size_t)r * 384 + dq * 4];
        *(float4*)&Ks[r][dq * 4] = *(const float4*)&base[(size_t)r * 384 + 128 + dq * 4];
        *(float4*)&Vs[r][dq * 4] = *(const float4*)&base[(size_t)r * 384 + 256 + dq * 4];
    }
    __syncthreads();
    int q = tid >> 2, kg = tid & 3;
    const float scale = 0.17677669529663687f;  // 1/sqrt(32)
    float p[16];
    float mx = -1e30f;
#pragma unroll
    for (int kk = 0; kk < 16; ++kk) {
        int k = kg * 16 + kk;
        float a = 0.f;
#pragma unroll
        for (int dq = 0; dq < 8; ++dq) {
            float4 qv = *(const float4*)&Qs[q][dq * 4];
            float4 kv = *(const float4*)&Ks[k][dq * 4];
            a += qv.x * kv.x + qv.y * kv.y + qv.z * kv.z + qv.w * kv.w;
        }
        p[kk] = a * scale;
        mx = fmaxf(mx, p[kk]);
    }
    mx = fmaxf(mx, __shfl_xor(mx, 1));
    mx = fmaxf(mx, __shfl_xor(mx, 2));
    float ssum = 0.f;
#pragma unroll
    for (int kk = 0; kk < 16; ++kk) {
        p[kk] = expf(p[kk] - mx);
        ssum += p[kk];
    }
    ssum += __shfl_xor(ssum, 1);
    ssum += __shfl_xor(ssum, 2);
    float inv = 1.f / ssum;
#pragma unroll
    for (int kk = 0; kk < 16; ++kk) Ss[q][kg * 16 + kk] = p[kk] * inv;
    __syncthreads();
    int dg = kg;
    float o[8] = {};
    for (int k = 0; k < 64; ++k) {
        float pw = Ss[q][k];
        float4 v0 = *(const float4*)&Vs[k][dg * 8];
        float4 v1 = *(const float4*)&Vs[k][dg * 8 + 4];
        o[0] += pw * v0.x; o[1] += pw * v0.y; o[2] += pw * v0.z; o[3] += pw * v0.w;
        o[4] += pw * v1.x; o[5] += pw * v1.y; o[6] += pw * v1.z; o[7] += pw * v1.w;
    }
    float* op = abuf + (size_t)(b * 64 + q) * DD + h * 32 + dg * 8;
    *(float4*)&op[0] = make_float4(o[0], o[1], o[2], o[3]);
    *(float4*)&op[4] = make_float4(o[4], o[5], o[6], o[7]);
}

__global__ __launch_bounds__(128) void k_head(
    const float* __restrict__ seq, const float* __restrict__ W1,
    const float* __restrict__ b1, const float* __restrict__ W2,
    const float* __restrict__ b2, float* __restrict__ out) {
    int b = blockIdx.x, t = threadIdx.x;
    __shared__ float pooled[DD];
    __shared__ float hid[64];
    float s = 0.f;
    for (int i = 0; i < TT; ++i) s += seq[(size_t)(b * TT + i) * DD + t];
    pooled[t] = s * (1.f / TT);
    __syncthreads();
    if (t < 64) {
        float a = b1[t];
        const float* wr = W1 + t * DD;
        for (int k = 0; k < DD; ++k) a += pooled[k] * wr[k];
        hid[t] = fmaxf(a, 0.f);
    }
    __syncthreads();
    if (t < 2) {
        float a = b2[t];
        const float* wr = W2 + t * 64;
        for (int k = 0; k < 64; ++k) a += hid[k] * wr[k];
        out[b * 2 + t] = a;
    }
}

// ---------------- host ----------------

extern "C" void kernel_launch(void* const* d_in, const int* in_sizes, int n_in,
                              void* d_out, int out_size, void* d_ws, size_t ws_size,
                              hipStream_t stream) {
    const float* x     = (const float*)d_in[0];
    const int*   esrc  = (const int*)d_in[1];
    const int*   edst  = (const int*)d_in[2];
    const float* gW1   = (const float*)d_in[4];
    const float* gb1   = (const float*)d_in[5];
    const float* ln1g  = (const float*)d_in[6];
    const float* ln1b  = (const float*)d_in[7];
    const float* gW2   = (const float*)d_in[8];
    const float* gb2   = (const float*)d_in[9];
    const float* ln2g  = (const float*)d_in[10];
    const float* ln2b  = (const float*)d_in[11];
    const float* gW3   = (const float*)d_in[12];
    const float* gb3   = (const float*)d_in[13];
    const float* tWqkv = (const float*)d_in[14];
    const float* tbqkv = (const float*)d_in[15];
    const float* tWo   = (const float*)d_in[16];
    const float* tbo   = (const float*)d_in[17];
    const float* tg1   = (const float*)d_in[18];
    const float* tb1   = (const float*)d_in[19];
    const float* tg2   = (const float*)d_in[20];
    const float* tb2   = (const float*)d_in[21];
    const float* tWf1  = (const float*)d_in[22];
    const float* tbf1  = (const float*)d_in[23];
    const float* tWf2  = (const float*)d_in[24];
    const float* tbf2  = (const float*)d_in[25];
    const float* hW1   = (const float*)d_in[26];
    const float* hb1   = (const float*)d_in[27];
    const float* hW2   = (const float*)d_in[28];
    const float* hb2   = (const float*)d_in[29];
    float* out = (float*)d_out;

    int*   cntN   = (int*)d_ws;              // NN  (memset together with cw)
    float* cw     = (float*)(cntN + NN);     // NN
    int*   gcnt   = (int*)(cw + NN);         // 512
    int*   gbase  = gcnt + GG;               // 513 (pad 516)
    int*   node_off = gbase + 516;           // NN+1 (pad NN+4)
    int*   cursorN  = node_off + NN + 4;     // NN
    uint2* epackN = (uint2*)(cursorN + NN);  // EE
    float* bufA = (float*)(epackN + EE);     // NN*64
    float* bufB = bufA + (size_t)NN * 64;    // NN*64
    float* pooled = bufB + (size_t)NN * 64;  // 512*64
    float* seq  = pooled + GG * 64;          // 512*128
    float* qkvb = seq + GG * DD;             // 512*384
    float* abuf = qkvb + GG * 384;           // 512*128
    float* f1b  = abuf + GG * DD;            // 512*512

    const int BS = 256;
    // CSR build (+ column sums cw)
    hipMemsetAsync(cntN, 0, 2 * NN * sizeof(int), stream);  // cntN and cw
    k_ncount<<<EE / BS, BS, 0, stream>>>(edst, cntN);
    k_gsum<<<GG, 64, 0, stream>>>(cntN, gcnt);
    k_gprefix<<<1, GG, 0, stream>>>(gcnt, gbase);
    k_nscan<<<GG, BS, 0, stream>>>(cntN, gbase, node_off, cursorN);
    k_escatter<<<EE / BS, BS, 0, stream>>>(esrc, edst, cntN, cursorN, epackN, cw);

    // GCN (XCD-swizzled, graph-aligned chunks)
    k_gcn1<<<NN / 50, BS, 0, stream>>>(x, gW1, gb1, ln1g, ln1b, cntN, node_off, epackN, bufA);
    k_agg_lin_ln<<<NN / 50, BS, 0, stream>>>(bufA, gW2, gb2, ln2g, ln2b, cntN, node_off,
                                             epackN, bufB);
    k_wpool<<<GG, BS, 0, stream>>>(bufB, cw, cntN, pooled);
    k_emb<<<GG, DD, 0, stream>>>(pooled, gW3, gb3, seq);

    // Transformer (row-major)
    for (int l = 0; l < LL; l++) {
        k_gemm<64, 64, 32, 128, false, false><<<dim3(6, 8), 256, 0, stream>>>(
            seq, tWqkv + (size_t)l * 384 * 128, tbqkv + l * 384,
            nullptr, nullptr, nullptr, qkvb, 384);
        k_attn<<<BB * 4, 256, 0, stream>>>(qkvb, abuf);
        k_gemm<16, 128, 32, 128, false, true><<<dim3(1, 32), 256, 0, stream>>>(
            abuf, tWo + (size_t)l * 128 * 128, tbo + l * 128,
            seq, tg1 + l * 128, tb1 + l * 128, seq, 128);
        k_gemm<64, 64, 32, 128, true, false><<<dim3(8, 8), 256, 0, stream>>>(
            seq, tWf1 + (size_t)l * 512 * 128, tbf1 + l * 512,
            nullptr, nullptr, nullptr, f1b, 512);
        k_gemm<16, 128, 32, 512, false, true><<<dim3(1, 32), 256, 0, stream>>>(
            f1b, tWf2 + (size_t)l * 128 * 512, tbf2 + l * 128,
            seq, tg2 + l * 128, tb2 + l * 128, seq, 128);
    }

    // head
    k_head<<<BB, DD, 0, stream>>>(seq, hW1, hb1, hW2, hb2, out);
}

// Round 9
// 520.888 us; speedup vs baseline: 1.4084x; 1.1781x over previous
//
#include <hip/hip_runtime.h>

#define NN   102400
#define EE   819200
#define GG   512
#define NPG  200
#define DD   128
#define TT   64
#define BB   8
#define LL   4

typedef unsigned int uint;

static __device__ __forceinline__ float wave_sum64(float v) {
#pragma unroll
    for (int off = 32; off > 0; off >>= 1) v += __shfl_xor(v, off, 64);
    return v;
}

static __device__ __forceinline__ void wave_sum64_2(float& a, float& b) {
#pragma unroll
    for (int off = 32; off > 0; off >>= 1) {
        a += __shfl_xor(a, off, 64);
        b += __shfl_xor(b, off, 64);
    }
}

// ---------------- CSR build (sort edges by dst node) ----------------

__global__ void k_ncount(const int* __restrict__ dst, int* __restrict__ cnt) {
    int e = blockIdx.x * blockDim.x + threadIdx.x;
    if (e < EE) atomicAdd(&cnt[dst[e]], 1);
}

__global__ __launch_bounds__(64) void k_gsum(const int* __restrict__ cnt,
                                             int* __restrict__ gcnt) {
    int g = blockIdx.x, t = threadIdx.x;
    int s = 0;
    for (int i = t; i < NPG; i += 64) s += cnt[g * NPG + i];
#pragma unroll
    for (int off = 32; off > 0; off >>= 1) s += __shfl_xor(s, off, 64);
    if (t == 0) gcnt[g] = s;
}

__global__ void k_gprefix(const int* __restrict__ gcnt, int* __restrict__ gbase) {
    __shared__ int sm[GG];
    int t = threadIdx.x;
    int c = gcnt[t];
    sm[t] = c;
    __syncthreads();
    for (int d = 1; d < GG; d <<= 1) {
        int v = (t >= d) ? sm[t - d] : 0;
        __syncthreads();
        sm[t] += v;
        __syncthreads();
    }
    gbase[t] = sm[t] - c;
    if (t == GG - 1) gbase[GG] = sm[t];
}

__global__ __launch_bounds__(256) void k_nscan(const int* __restrict__ cnt,
                                               const int* __restrict__ gbase,
                                               int* __restrict__ node_off,
                                               int* __restrict__ cursorN) {
    int g = blockIdx.x, t = threadIdx.x;
    __shared__ int sm[256];
    int c = (t < NPG) ? cnt[g * NPG + t] : 0;
    sm[t] = c;
    __syncthreads();
    for (int d = 1; d < 256; d <<= 1) {
        int v = (t >= d) ? sm[t - d] : 0;
        __syncthreads();
        sm[t] += v;
        __syncthreads();
    }
    if (t < NPG) {
        int off = gbase[g] + sm[t] - c;
        node_off[g * NPG + t] = off;
        cursorN[g * NPG + t] = off;
    }
    if (g == GG - 1 && t == 0) node_off[NN] = gbase[GG];
}

// also accumulates column sums of A_hat (cw[src] += w) for the pooled-readout algebra
__global__ void k_escatter(const int* __restrict__ src, const int* __restrict__ dst,
                           const int* __restrict__ cnt, int* __restrict__ cursorN,
                           uint2* __restrict__ epackN, float* __restrict__ cw) {
    int e = blockIdx.x * blockDim.x + threadIdx.x;
    if (e >= EE) return;
    int s = src[e], d = dst[e];
    int pos = atomicAdd(&cursorN[d], 1);
    float w = rsqrtf((float)(cnt[s] + 1)) * rsqrtf((float)(cnt[d] + 1));
    epackN[pos] = make_uint2((uint)s, __float_as_uint(w));
    atomicAdd(&cw[s], w);
}

// ---------------- GCN (XCD-swizzled, graph-aligned 50-node chunks) ----------------

// layer 1: agg x (2-wide) + 2->64 transform + bias/relu/LN
__global__ __launch_bounds__(256) void k_gcn1(
    const float* __restrict__ x, const float* __restrict__ W1,
    const float* __restrict__ gb1, const float* __restrict__ lng,
    const float* __restrict__ lnb, const int* __restrict__ cnt,
    const int* __restrict__ node_off, const uint2* __restrict__ epackN,
    float* __restrict__ hout) {
    int c = ((blockIdx.x & 7) << 8) | (blockIdx.x >> 3);
    int n0 = c * 50;
    __shared__ int noff[51];
    __shared__ float dinvs[50];
    int tid = threadIdx.x, lane = tid & 63, wid = tid >> 6;
    if (tid <= 50) noff[tid] = node_off[n0 + tid];
    if (tid < 50) dinvs[tid] = 1.f / (float)(cnt[n0 + tid] + 1);
    __syncthreads();
    const float2* x2 = (const float2*)x;
    float w0 = W1[lane], w1 = W1[64 + lane];
    float gbj = gb1[lane], lgj = lng[lane], lbj = lnb[lane];
    for (int i = wid; i < 50; i += 4) {
        int e0 = noff[i], E = noff[i + 1] - e0;
        float wx = 0.f, wy = 0.f;
        if (lane < E) {
            uint2 my = epackN[e0 + lane];
            float w = __uint_as_float(my.y);
            float2 xe = x2[my.x];
            wx = xe.x * w;
            wy = xe.y * w;
        }
        for (int e = 64; e < E; ++e) {  // rare tail
            uint2 ed = epackN[e0 + e];
            if (lane == 0) {
                float w = __uint_as_float(ed.y);
                float2 xe = x2[ed.x];
                wx += xe.x * w;
                wy += xe.y * w;
            }
        }
        wave_sum64_2(wx, wy);
        float2 xv = x2[n0 + i];
        wx += xv.x * dinvs[i];
        wy += xv.y * dinvs[i];
        float u = fmaxf(wx * w0 + wy * w1 + gbj, 0.f);
        float s = u, q = u * u;
        wave_sum64_2(s, q);
        float mean = s * (1.f / 64.f);
        float var = q * (1.f / 64.f) - mean * mean;
        hout[(size_t)(n0 + i) * 64 + lane] = (u - mean) * rsqrtf(var + 1e-5f) * lgj + lbj;
    }
}

// fused layer 2: z = A_hat*t (slot-parallel float4 gather), h = LN(relu(z@W2+b2))
__global__ __launch_bounds__(256) void k_agg_lin_ln(
    const float* __restrict__ t, const float* __restrict__ W,
    const float* __restrict__ gb, const float* __restrict__ lng,
    const float* __restrict__ lnb, const int* __restrict__ cnt,
    const int* __restrict__ node_off, const uint2* __restrict__ epackN,
    float* __restrict__ hout) {
    int c = ((blockIdx.x & 7) << 8) | (blockIdx.x >> 3);
    int n0 = c * 50;
    __shared__ float hs[50][64];
    __shared__ int noff[51];
    __shared__ float dinvs[50];
    int tid = threadIdx.x, lane = tid & 63, wid = tid >> 6;
    int grp = lane >> 4, fq = lane & 15;
    if (tid <= 50) noff[tid] = node_off[n0 + tid];
    if (tid < 50) dinvs[tid] = 1.f / (float)(cnt[n0 + tid] + 1);
    __syncthreads();
    // gather phase: 4 edges per load instruction (lane = grp x featquad)
    for (int i = wid; i < 50; i += 4) {
        int e0 = noff[i], E = noff[i + 1] - e0;
        uint2 my = make_uint2(0u, 0u);
        if (lane < E) my = epackN[e0 + lane];
        float4 acc = make_float4(0.f, 0.f, 0.f, 0.f);
        if (grp == 0) {
            float4 tv = *(const float4*)&t[(size_t)(n0 + i) * 64 + fq * 4];
            float dv = dinvs[i];
            acc = make_float4(tv.x * dv, tv.y * dv, tv.z * dv, tv.w * dv);
        }
        int El = E < 64 ? E : 64;
        for (int base = 0; base < El; base += 4) {
            int e = base + grp;
            int s = __shfl((int)my.x, e);
            float w = __shfl(__uint_as_float(my.y), e);
            if (e < El) {
                float4 tv = *(const float4*)&t[(size_t)s * 64 + fq * 4];
                acc.x += tv.x * w; acc.y += tv.y * w;
                acc.z += tv.z * w; acc.w += tv.w * w;
            }
        }
        for (int e = 64 + grp; e < E; e += 4) {  // rare tail
            uint2 ed = epackN[e0 + e];
            float w = __uint_as_float(ed.y);
            float4 tv = *(const float4*)&t[(size_t)ed.x * 64 + fq * 4];
            acc.x += tv.x * w; acc.y += tv.y * w;
            acc.z += tv.z * w; acc.w += tv.w * w;
        }
        // reduce across the 4 edge-slots
        acc.x += __shfl_xor(acc.x, 16); acc.y += __shfl_xor(acc.y, 16);
        acc.z += __shfl_xor(acc.z, 16); acc.w += __shfl_xor(acc.w, 16);
        acc.x += __shfl_xor(acc.x, 32); acc.y += __shfl_xor(acc.y, 32);
        acc.z += __shfl_xor(acc.z, 32); acc.w += __shfl_xor(acc.w, 32);
        if (grp == 0) *(float4*)&hs[i][fq * 4] = acc;
    }
    // W column cached in registers (W2 is 16KB, L2-hot; overlap load with sync)
    float wreg[64];
#pragma unroll
    for (int k = 0; k < 64; ++k) wreg[k] = W[k * 64 + lane];
    __syncthreads();
    float gbj = gb[lane], lgj = lng[lane], lbj = lnb[lane];
    for (int i = wid; i < 50; i += 4) {
        const float4* hrow = (const float4*)&hs[i][0];
        float a0 = 0.f, a1 = 0.f;
#pragma unroll
        for (int k4 = 0; k4 < 16; k4 += 2) {
            float4 h0 = hrow[k4], h1 = hrow[k4 + 1];
            a0 += h0.x * wreg[4 * k4] + h0.y * wreg[4 * k4 + 1] +
                  h0.z * wreg[4 * k4 + 2] + h0.w * wreg[4 * k4 + 3];
            a1 += h1.x * wreg[4 * k4 + 4] + h1.y * wreg[4 * k4 + 5] +
                  h1.z * wreg[4 * k4 + 6] + h1.w * wreg[4 * k4 + 7];
        }
        float u = fmaxf(a0 + a1 + gbj, 0.f);
        float s = u, q = u * u;
        wave_sum64_2(s, q);
        float mean = s * (1.f / 64.f);
        float var = q * (1.f / 64.f) - mean * mean;
        hout[(size_t)(n0 + i) * 64 + lane] = (u - mean) * rsqrtf(var + 1e-5f) * lgj + lbj;
    }
}

// layer 3 + readout + 64->128 transform + PE, fused
__global__ __launch_bounds__(256) void k_wpool_emb(
    const float* __restrict__ h2, const float* __restrict__ cw,
    const int* __restrict__ cnt, const float* __restrict__ W3,
    const float* __restrict__ b3, float* __restrict__ seq) {
    int g = ((blockIdx.x & 7) << 6) | (blockIdx.x >> 3);
    int n0 = g * NPG;
    __shared__ float wgt[NPG];
    __shared__ float red[4][64];
    __shared__ float ps[64];
    int tid = threadIdx.x, lane = tid & 63, wid = tid >> 6;
    for (int i = tid; i < NPG; i += 256)
        wgt[i] = cw[n0 + i] + 1.f / (float)(cnt[n0 + i] + 1);
    __syncthreads();
    float acc = 0.f;
    for (int i = wid; i < NPG; i += 4)
        acc += h2[(size_t)(n0 + i) * 64 + lane] * wgt[i];
    red[wid][lane] = acc;
    __syncthreads();
    if (tid < 64)
        ps[tid] = (red[0][tid] + red[1][tid] + red[2][tid] + red[3][tid]) * (1.f / NPG);
    __syncthreads();
    if (tid < 128) {
        int d = tid;
        float a = b3[d];
#pragma unroll 8
        for (int k = 0; k < 64; ++k) a += ps[k] * W3[k * DD + d];
        float freq = expf((float)(d & ~1) * (-9.210340371976184f / 128.f));
        float ang = (float)(g & (TT - 1)) * freq;
        a += (d & 1) ? cosf(ang) : sinf(ang);
        seq[(size_t)g * DD + d] = a;
    }
}

// ---------------- Transformer (row-major, tiled GEMMs, fused LN) ----------------

template <int BM, int BN, int BK, int K, bool RELU, bool RESLN>
__global__ __launch_bounds__(256) void k_gemm(
    const float* __restrict__ A, const float* __restrict__ W,
    const float* __restrict__ bias, const float* __restrict__ res,
    const float* __restrict__ lng, const float* __restrict__ lnb,
    float* __restrict__ C, int N) {
    constexpr int TX = BN / 4;
    constexpr int TY = 256 / TX;
    constexpr int MR = BM / TY;      // rows per thread
    __shared__ float as[BK][BM + 4];
    __shared__ float ws[BK][BN + 4];
    __shared__ float smc[RESLN ? BM * (BN + 4) : 4];
    int tid = threadIdx.x;
    int r0 = blockIdx.y * BM, c0 = blockIdx.x * BN;
    int tx = tid % TX, ty = tid / TX;
    float acc[MR][4] = {};
    for (int k0 = 0; k0 < K; k0 += BK) {
        for (int li = tid; li < BM * BK / 4; li += 256) {
            int r = li / (BK / 4), kq = li % (BK / 4);
            float4 v = *(const float4*)&A[(size_t)(r0 + r) * K + k0 + kq * 4];
            as[kq * 4 + 0][r] = v.x; as[kq * 4 + 1][r] = v.y;
            as[kq * 4 + 2][r] = v.z; as[kq * 4 + 3][r] = v.w;
        }
        for (int li = tid; li < BN * BK / 4; li += 256) {
            int cc = li / (BK / 4), kq = li % (BK / 4);
            float4 v = *(const float4*)&W[(size_t)(c0 + cc) * K + k0 + kq * 4];
            ws[kq * 4 + 0][cc] = v.x; ws[kq * 4 + 1][cc] = v.y;
            ws[kq * 4 + 2][cc] = v.z; ws[kq * 4 + 3][cc] = v.w;
        }
        __syncthreads();
#pragma unroll
        for (int k = 0; k < BK; ++k) {
            float4 wv = *(const float4*)&ws[k][tx * 4];
            float w4[4] = {wv.x, wv.y, wv.z, wv.w};
#pragma unroll
            for (int i = 0; i < MR; ++i) {
                float a = as[k][ty * MR + i];
#pragma unroll
                for (int j = 0; j < 4; ++j) acc[i][j] += a * w4[j];
            }
        }
        __syncthreads();
    }
    float4 bv = *(const float4*)&bias[c0 + tx * 4];
    float b4[4] = {bv.x, bv.y, bv.z, bv.w};
    if constexpr (!RESLN) {
#pragma unroll
        for (int i = 0; i < MR; ++i) {
            float4 o;
            o.x = acc[i][0] + b4[0]; o.y = acc[i][1] + b4[1];
            o.z = acc[i][2] + b4[2]; o.w = acc[i][3] + b4[3];
            if (RELU) {
                o.x = fmaxf(o.x, 0.f); o.y = fmaxf(o.y, 0.f);
                o.z = fmaxf(o.z, 0.f); o.w = fmaxf(o.w, 0.f);
            }
            *(float4*)&C[(size_t)(r0 + ty * MR + i) * N + c0 + tx * 4] = o;
        }
    } else {
        float(*sm)[BN + 4] = (float(*)[BN + 4])smc;
#pragma unroll
        for (int i = 0; i < MR; ++i) {
            float4 r4 = *(const float4*)&res[(size_t)(r0 + ty * MR + i) * N + tx * 4];
            sm[ty * MR + i][tx * 4 + 0] = acc[i][0] + b4[0] + r4.x;
            sm[ty * MR + i][tx * 4 + 1] = acc[i][1] + b4[1] + r4.y;
            sm[ty * MR + i][tx * 4 + 2] = acc[i][2] + b4[2] + r4.z;
            sm[ty * MR + i][tx * 4 + 3] = acc[i][3] + b4[3] + r4.w;
        }
        __syncthreads();
        int wv_ = tid >> 6, ln = tid & 63;
        for (int r = wv_ * (BM / 4); r < (wv_ + 1) * (BM / 4); ++r) {
            float v0 = sm[r][ln], v1 = sm[r][ln + 64];
            float s = v0 + v1, q = v0 * v0 + v1 * v1;
            wave_sum64_2(s, q);
            float mean = s * (1.f / 128.f);
            float var = q * (1.f / 128.f) - mean * mean;
            float rstd = rsqrtf(var + 1e-5f);
            C[(size_t)(r0 + r) * N + ln] = (v0 - mean) * rstd * lng[ln] + lnb[ln];
            C[(size_t)(r0 + r) * N + ln + 64] =
                (v1 - mean) * rstd * lng[ln + 64] + lnb[ln + 64];
        }
    }
}

// attention: block per (b,h), 256 threads
__global__ __launch_bounds__(256) void k_attn(const float* __restrict__ qkv,
                                              float* __restrict__ abuf) {
    int b = blockIdx.x >> 2, h = blockIdx.x & 3;
    __shared__ float Qs[64][36], Ks[64][36], Vs[64][36];
    __shared__ float Ss[64][68];
    int tid = threadIdx.x;
    const float* base = qkv + (size_t)(b * 64) * 384 + h * 32;
    for (int li = tid; li < 512; li += 256) {
        int r = li >> 3, dq = li & 7;
        *(float4*)&Qs[r][dq * 4] = *(const float4*)&base[(size_t)r * 384 + dq * 4];
        *(float4*)&Ks[r][dq * 4] = *(const float4*)&base[(size_t)r * 384 + 128 + dq * 4];
        *(float4*)&Vs[r][dq * 4] = *(const float4*)&base[(size_t)r * 384 + 256 + dq * 4];
    }
    __syncthreads();
    int q = tid >> 2, kg = tid & 3;
    const float scale = 0.17677669529663687f;  // 1/sqrt(32)
    float p[16];
    float mx = -1e30f;
#pragma unroll
    for (int kk = 0; kk < 16; ++kk) {
        int k = kg * 16 + kk;
        float a = 0.f;
#pragma unroll
        for (int dq = 0; dq < 8; ++dq) {
            float4 qv = *(const float4*)&Qs[q][dq * 4];
            float4 kv = *(const float4*)&Ks[k][dq * 4];
            a += qv.x * kv.x + qv.y * kv.y + qv.z * kv.z + qv.w * kv.w;
        }
        p[kk] = a * scale;
        mx = fmaxf(mx, p[kk]);
    }
    mx = fmaxf(mx, __shfl_xor(mx, 1));
    mx = fmaxf(mx, __shfl_xor(mx, 2));
    float ssum = 0.f;
#pragma unroll
    for (int kk = 0; kk < 16; ++kk) {
        p[kk] = expf(p[kk] - mx);
        ssum += p[kk];
    }
    ssum += __shfl_xor(ssum, 1);
    ssum += __shfl_xor(ssum, 2);
    float inv = 1.f / ssum;
#pragma unroll
    for (int kk = 0; kk < 16; ++kk) Ss[q][kg * 16 + kk] = p[kk] * inv;
    __syncthreads();
    int dg = kg;
    float o[8] = {};
    for (int k = 0; k < 64; ++k) {
        float pw = Ss[q][k];
        float4 v0 = *(const float4*)&Vs[k][dg * 8];
        float4 v1 = *(const float4*)&Vs[k][dg * 8 + 4];
        o[0] += pw * v0.x; o[1] += pw * v0.y; o[2] += pw * v0.z; o[3] += pw * v0.w;
        o[4] += pw * v1.x; o[5] += pw * v1.y; o[6] += pw * v1.z; o[7] += pw * v1.w;
    }
    float* op = abuf + (size_t)(b * 64 + q) * DD + h * 32 + dg * 8;
    *(float4*)&op[0] = make_float4(o[0], o[1], o[2], o[3]);
    *(float4*)&op[4] = make_float4(o[4], o[5], o[6], o[7]);
}

__global__ __launch_bounds__(128) void k_head(
    const float* __restrict__ seq, const float* __restrict__ W1,
    const float* __restrict__ b1, const float* __restrict__ W2,
    const float* __restrict__ b2, float* __restrict__ out) {
    int b = blockIdx.x, t = threadIdx.x;
    __shared__ float pooled[DD];
    __shared__ float hid[64];
    float s = 0.f;
    for (int i = 0; i < TT; ++i) s += seq[(size_t)(b * TT + i) * DD + t];
    pooled[t] = s * (1.f / TT);
    __syncthreads();
    if (t < 64) {
        float a = b1[t];
        const float* wr = W1 + t * DD;
        for (int k = 0; k < DD; ++k) a += pooled[k] * wr[k];
        hid[t] = fmaxf(a, 0.f);
    }
    __syncthreads();
    if (t < 2) {
        float a = b2[t];
        const float* wr = W2 + t * 64;
        for (int k = 0; k < 64; ++k) a += hid[k] * wr[k];
        out[b * 2 + t] = a;
    }
}

// ---------------- host ----------------

extern "C" void kernel_launch(void* const* d_in, const int* in_sizes, int n_in,
                              void* d_out, int out_size, void* d_ws, size_t ws_size,
                              hipStream_t stream) {
    const float* x     = (const float*)d_in[0];
    const int*   esrc  = (const int*)d_in[1];
    const int*   edst  = (const int*)d_in[2];
    const float* gW1   = (const float*)d_in[4];
    const float* gb1   = (const float*)d_in[5];
    const float* ln1g  = (const float*)d_in[6];
    const float* ln1b  = (const float*)d_in[7];
    const float* gW2   = (const float*)d_in[8];
    const float* gb2   = (const float*)d_in[9];
    const float* ln2g  = (const float*)d_in[10];
    const float* ln2b  = (const float*)d_in[11];
    const float* gW3   = (const float*)d_in[12];
    const float* gb3   = (const float*)d_in[13];
    const float* tWqkv = (const float*)d_in[14];
    const float* tbqkv = (const float*)d_in[15];
    const float* tWo   = (const float*)d_in[16];
    const float* tbo   = (const float*)d_in[17];
    const float* tg1   = (const float*)d_in[18];
    const float* tb1   = (const float*)d_in[19];
    const float* tg2   = (const float*)d_in[20];
    const float* tb2   = (const float*)d_in[21];
    const float* tWf1  = (const float*)d_in[22];
    const float* tbf1  = (const float*)d_in[23];
    const float* tWf2  = (const float*)d_in[24];
    const float* tbf2  = (const float*)d_in[25];
    const float* hW1   = (const float*)d_in[26];
    const float* hb1   = (const float*)d_in[27];
    const float* hW2   = (const float*)d_in[28];
    const float* hb2   = (const float*)d_in[29];
    float* out = (float*)d_out;

    int*   cntN   = (int*)d_ws;              // NN  (memset together with cw)
    float* cw     = (float*)(cntN + NN);     // NN
    int*   gcnt   = (int*)(cw + NN);         // 512
    int*   gbase  = gcnt + GG;               // 513 (pad 516)
    int*   node_off = gbase + 516;           // NN+1 (pad NN+4)
    int*   cursorN  = node_off + NN + 4;     // NN
    uint2* epackN = (uint2*)(cursorN + NN);  // EE
    float* bufA = (float*)(epackN + EE);     // NN*64
    float* bufB = bufA + (size_t)NN * 64;    // NN*64
    float* seq  = bufB + (size_t)NN * 64;    // 512*128
    float* qkvb = seq + GG * DD;             // 512*384
    float* abuf = qkvb + GG * 384;           // 512*128
    float* f1b  = abuf + GG * DD;            // 512*512

    const int BS = 256;
    // CSR build (+ column sums cw)
    hipMemsetAsync(cntN, 0, 2 * NN * sizeof(int), stream);  // cntN and cw
    k_ncount<<<EE / BS, BS, 0, stream>>>(edst, cntN);
    k_gsum<<<GG, 64, 0, stream>>>(cntN, gcnt);
    k_gprefix<<<1, GG, 0, stream>>>(gcnt, gbase);
    k_nscan<<<GG, BS, 0, stream>>>(cntN, gbase, node_off, cursorN);
    k_escatter<<<EE / BS, BS, 0, stream>>>(esrc, edst, cntN, cursorN, epackN, cw);

    // GCN
    k_gcn1<<<NN / 50, BS, 0, stream>>>(x, gW1, gb1, ln1g, ln1b, cntN, node_off, epackN, bufA);
    k_agg_lin_ln<<<NN / 50, BS, 0, stream>>>(bufA, gW2, gb2, ln2g, ln2b, cntN, node_off,
                                             epackN, bufB);
    k_wpool_emb<<<GG, BS, 0, stream>>>(bufB, cw, cntN, gW3, gb3, seq);

    // Transformer (row-major)
    for (int l = 0; l < LL; l++) {
        k_gemm<32, 32, 32, 128, false, false><<<dim3(12, 16), 256, 0, stream>>>(
            seq, tWqkv + (size_t)l * 384 * 128, tbqkv + l * 384,
            nullptr, nullptr, nullptr, qkvb, 384);
        k_attn<<<BB * 4, 256, 0, stream>>>(qkvb, abuf);
        k_gemm<8, 128, 32, 128, false, true><<<dim3(1, 64), 256, 0, stream>>>(
            abuf, tWo + (size_t)l * 128 * 128, tbo + l * 128,
            seq, tg1 + l * 128, tb1 + l * 128, seq, 128);
        k_gemm<32, 32, 32, 128, true, false><<<dim3(16, 16), 256, 0, stream>>>(
            seq, tWf1 + (size_t)l * 512 * 128, tbf1 + l * 512,
            nullptr, nullptr, nullptr, f1b, 512);
        k_gemm<8, 128, 32, 512, false, true><<<dim3(1, 64), 256, 0, stream>>>(
            f1b, tWf2 + (size_t)l * 128 * 512, tbf2 + l * 128,
            seq, tg2 + l * 128, tb2 + l * 128, seq, 128);
    }

    // head
    k_head<<<BB, DD, 0, stream>>>(seq, hW1, hb1, hW2, hb2, out);
}

// Round 10
// 431.656 us; speedup vs baseline: 1.6995x; 1.2067x over previous
//
#include <hip/hip_runtime.h>

#define NN   102400
#define EE   819200
#define GG   512
#define NPG  200
#define DD   128
#define TT   64
#define BB   8
#define LL   4
#define ECHUNK 12800   // EE / 64
#define SCAP 2560      // per-graph sorted-edge LDS capacity (lambda=1600, 24 sigma)

typedef unsigned int uint;

static __device__ __forceinline__ void wave_sum64_2(float& a, float& b) {
#pragma unroll
    for (int off = 32; off > 0; off >>= 1) {
        a += __shfl_xor(a, off, 64);
        b += __shfl_xor(b, off, 64);
    }
}

// ---------------- CSR build: coalesced two-level counting sort ----------------

// A1: per-block histogram by graph
__global__ __launch_bounds__(256) void k_a1(const int* __restrict__ src,
                                            int* __restrict__ hist) {
    __shared__ int h[GG];
    int tid = threadIdx.x;
    h[tid] = 0; h[tid + 256] = 0;
    __syncthreads();
    int base = blockIdx.x * ECHUNK;
#pragma unroll 2
    for (int it = 0; it < 50; ++it)
        atomicAdd(&h[src[base + it * 256 + tid] / NPG], 1);
    __syncthreads();
    hist[blockIdx.x * GG + tid] = h[tid];
    hist[blockIdx.x * GG + tid + 256] = h[tid + 256];
}

// A2: graph bases + per-(block,graph) cursors
__global__ __launch_bounds__(512) void k_a2(const int* __restrict__ hist,
                                            int* __restrict__ off2,
                                            int* __restrict__ goff) {
    __shared__ int sm[GG];
    int g = threadIdx.x;
    int s = 0;
    for (int b = 0; b < 64; ++b) s += hist[b * GG + g];
    sm[g] = s;
    __syncthreads();
    for (int d = 1; d < GG; d <<= 1) {
        int v = (g >= d) ? sm[g - d] : 0;
        __syncthreads();
        sm[g] += v;
        __syncthreads();
    }
    int base = sm[g] - s;
    goff[g] = base;
    if (g == GG - 1) goff[GG] = sm[g];
    int run = base;
    for (int b = 0; b < 64; ++b) {
        off2[b * GG + g] = run;
        run += hist[b * GG + g];
    }
}

// A3: binned scatter of packed (lsrc<<8|ldst); per-(block,graph) streams are sequential
__global__ __launch_bounds__(256) void k_a3(const int* __restrict__ src,
                                            const int* __restrict__ dst,
                                            const int* __restrict__ off2,
                                            uint* __restrict__ gpack) {
    __shared__ int cur[GG];
    int tid = threadIdx.x;
    cur[tid] = off2[blockIdx.x * GG + tid];
    cur[tid + 256] = off2[blockIdx.x * GG + tid + 256];
    __syncthreads();
    int base = blockIdx.x * ECHUNK;
    for (int it = 0; it < 50; ++it) {
        int e = base + it * 256 + tid;
        int s = src[e], d = dst[e];
        int g = s / NPG;
        int pos = atomicAdd(&cur[g], 1);
        gpack[pos] = ((uint)(s - g * NPG) << 8) | (uint)(d - g * NPG);
    }
}

// B: per-graph in-LDS counting sort by dst + epackN/node_off/deginv/wgt emit +
//    fused layer-1 x-aggregation (all writes coalesced; zero global atomics)
__global__ __launch_bounds__(256) void k_bsort(
    const float* __restrict__ x, const int* __restrict__ goff,
    const uint* __restrict__ gpack, uint2* __restrict__ epackN,
    int* __restrict__ node_off, float* __restrict__ deginv,
    float* __restrict__ wgtv, float2* __restrict__ aggx) {
    int g = ((blockIdx.x & 7) << 6) | (blockIdx.x >> 3);  // XCD-local graphs
    __shared__ float2 xs[NPG];
    __shared__ int cnt2[NPG];
    __shared__ int lnoff[NPG + 1];
    __shared__ int cur[NPG];
    __shared__ float rsq[NPG];
    __shared__ float cwl[NPG];
    __shared__ uint srec[SCAP];
    __shared__ int sm[256];
    int tid = threadIdx.x;
    int base = goff[g], E = goff[g + 1] - base;
    const float2* x2 = (const float2*)x;
    if (tid < NPG) {
        xs[tid] = x2[g * NPG + tid];
        cnt2[tid] = 0;
        cwl[tid] = 0.f;
    }
    __syncthreads();
    for (int i = tid; i < E; i += 256) atomicAdd(&cnt2[gpack[base + i] & 255u], 1);
    __syncthreads();
    int c = (tid < NPG) ? cnt2[tid] : 0;
    sm[tid] = c;
    __syncthreads();
    for (int d = 1; d < 256; d <<= 1) {
        int v = (tid >= d) ? sm[tid - d] : 0;
        __syncthreads();
        sm[tid] += v;
        __syncthreads();
    }
    if (tid < NPG) {
        lnoff[tid] = sm[tid] - c;
        cur[tid] = sm[tid] - c;
        rsq[tid] = rsqrtf((float)(c + 1));
    }
    if (tid == 0) lnoff[NPG] = E;
    __syncthreads();
    for (int i = tid; i < E; i += 256) {
        uint r = gpack[base + i];
        int pos = atomicAdd(&cur[r & 255u], 1);
        srec[pos] = r;
    }
    __syncthreads();
    // coalesced emit + column-sum accumulation
    for (int i = tid; i < E; i += 256) {
        uint r = srec[i];
        int ls = r >> 8, ld = r & 255u;
        float w = rsq[ls] * rsq[ld];
        epackN[base + i] = make_uint2((uint)(g * NPG + ls), __float_as_uint(w));
        atomicAdd(&cwl[ls], w);
    }
    __syncthreads();
    if (tid < NPG) {
        float dv = rsq[tid] * rsq[tid];  // 1/deg
        float ax = xs[tid].x * dv, ay = xs[tid].y * dv;
        int e1 = lnoff[tid + 1];
        for (int e = lnoff[tid]; e < e1; ++e) {
            uint r = srec[e];
            int ls = r >> 8;
            float w = rsq[ls] * rsq[tid];
            ax += xs[ls].x * w;
            ay += xs[ls].y * w;
        }
        int n = g * NPG + tid;
        aggx[n] = make_float2(ax, ay);
        node_off[n] = base + lnoff[tid];
        deginv[n] = dv;
        wgtv[n] = cwl[tid] + dv;
    }
    if (g == GG - 1 && tid == 0) node_off[NN] = base + E;
}

// ---------------- GCN ----------------

// layer 1 (edge-free): h1 = LN(relu(aggx @ W1 + b1)) — streaming, XCD-colocated
__global__ __launch_bounds__(256) void k_gcn1t(
    const float2* __restrict__ aggx, const float* __restrict__ W1,
    const float* __restrict__ gb1, const float* __restrict__ lng,
    const float* __restrict__ lnb, float* __restrict__ hout) {
    int n0 = (blockIdx.x & 7) * 12800 + (blockIdx.x >> 3) * 64;  // 1600 blocks
    int tid = threadIdx.x, lane = tid & 63, wid = tid >> 6;
    float w0 = W1[lane], w1 = W1[64 + lane];
    float gbj = gb1[lane], lgj = lng[lane], lbj = lnb[lane];
    for (int i = wid; i < 64; i += 4) {
        float2 a = aggx[n0 + i];
        float u = fmaxf(a.x * w0 + a.y * w1 + gbj, 0.f);
        float s = u, q = u * u;
        wave_sum64_2(s, q);
        float mean = s * (1.f / 64.f);
        float var = q * (1.f / 64.f) - mean * mean;
        hout[(size_t)(n0 + i) * 64 + lane] = (u - mean) * rsqrtf(var + 1e-5f) * lgj + lbj;
    }
}

// fused layer 2: z = A_hat*t (slot-parallel float4 gather), h = LN(relu(z@W2+b2))
__global__ __launch_bounds__(256) void k_agg_lin_ln(
    const float* __restrict__ t, const float* __restrict__ W,
    const float* __restrict__ gb, const float* __restrict__ lng,
    const float* __restrict__ lnb, const float* __restrict__ deginv,
    const int* __restrict__ node_off, const uint2* __restrict__ epackN,
    float* __restrict__ hout) {
    int c = ((blockIdx.x & 7) << 8) | (blockIdx.x >> 3);
    int n0 = c * 50;
    __shared__ float hs[50][64];
    __shared__ int noff[51];
    __shared__ float dinvs[50];
    int tid = threadIdx.x, lane = tid & 63, wid = tid >> 6;
    int grp = lane >> 4, fq = lane & 15;
    if (tid <= 50) noff[tid] = node_off[n0 + tid];
    if (tid < 50) dinvs[tid] = deginv[n0 + tid];
    __syncthreads();
    for (int i = wid; i < 50; i += 4) {
        int e0 = noff[i], E = noff[i + 1] - e0;
        uint2 my = make_uint2(0u, 0u);
        if (lane < E) my = epackN[e0 + lane];
        float4 acc = make_float4(0.f, 0.f, 0.f, 0.f);
        if (grp == 0) {
            float4 tv = *(const float4*)&t[(size_t)(n0 + i) * 64 + fq * 4];
            float dv = dinvs[i];
            acc = make_float4(tv.x * dv, tv.y * dv, tv.z * dv, tv.w * dv);
        }
        int El = E < 64 ? E : 64;
        for (int base = 0; base < El; base += 4) {
            int e = base + grp;
            int s = __shfl((int)my.x, e);
            float w = __shfl(__uint_as_float(my.y), e);
            if (e < El) {
                float4 tv = *(const float4*)&t[(size_t)s * 64 + fq * 4];
                acc.x += tv.x * w; acc.y += tv.y * w;
                acc.z += tv.z * w; acc.w += tv.w * w;
            }
        }
        for (int e = 64 + grp; e < E; e += 4) {  // rare tail
            uint2 ed = epackN[e0 + e];
            float w = __uint_as_float(ed.y);
            float4 tv = *(const float4*)&t[(size_t)ed.x * 64 + fq * 4];
            acc.x += tv.x * w; acc.y += tv.y * w;
            acc.z += tv.z * w; acc.w += tv.w * w;
        }
        acc.x += __shfl_xor(acc.x, 16); acc.y += __shfl_xor(acc.y, 16);
        acc.z += __shfl_xor(acc.z, 16); acc.w += __shfl_xor(acc.w, 16);
        acc.x += __shfl_xor(acc.x, 32); acc.y += __shfl_xor(acc.y, 32);
        acc.z += __shfl_xor(acc.z, 32); acc.w += __shfl_xor(acc.w, 32);
        if (grp == 0) *(float4*)&hs[i][fq * 4] = acc;
    }
    float wreg[64];
#pragma unroll
    for (int k = 0; k < 64; ++k) wreg[k] = W[k * 64 + lane];
    __syncthreads();
    float gbj = gb[lane], lgj = lng[lane], lbj = lnb[lane];
    for (int i = wid; i < 50; i += 4) {
        const float4* hrow = (const float4*)&hs[i][0];
        float a0 = 0.f, a1 = 0.f;
#pragma unroll
        for (int k4 = 0; k4 < 16; k4 += 2) {
            float4 h0 = hrow[k4], h1 = hrow[k4 + 1];
            a0 += h0.x * wreg[4 * k4] + h0.y * wreg[4 * k4 + 1] +
                  h0.z * wreg[4 * k4 + 2] + h0.w * wreg[4 * k4 + 3];
            a1 += h1.x * wreg[4 * k4 + 4] + h1.y * wreg[4 * k4 + 5] +
                  h1.z * wreg[4 * k4 + 6] + h1.w * wreg[4 * k4 + 7];
        }
        float u = fmaxf(a0 + a1 + gbj, 0.f);
        float s = u, q = u * u;
        wave_sum64_2(s, q);
        float mean = s * (1.f / 64.f);
        float var = q * (1.f / 64.f) - mean * mean;
        hout[(size_t)(n0 + i) * 64 + lane] = (u - mean) * rsqrtf(var + 1e-5f) * lgj + lbj;
    }
}

// layer 3 + readout + 64->128 transform + PE, fused
__global__ __launch_bounds__(256) void k_wpool_emb(
    const float* __restrict__ h2, const float* __restrict__ wgtv,
    const float* __restrict__ W3, const float* __restrict__ b3,
    float* __restrict__ seq) {
    int g = ((blockIdx.x & 7) << 6) | (blockIdx.x >> 3);
    int n0 = g * NPG;
    __shared__ float wgt[NPG];
    __shared__ float red[4][64];
    __shared__ float ps[64];
    int tid = threadIdx.x, lane = tid & 63, wid = tid >> 6;
    for (int i = tid; i < NPG; i += 256) wgt[i] = wgtv[n0 + i];
    __syncthreads();
    float acc = 0.f;
    for (int i = wid; i < NPG; i += 4)
        acc += h2[(size_t)(n0 + i) * 64 + lane] * wgt[i];
    red[wid][lane] = acc;
    __syncthreads();
    if (tid < 64)
        ps[tid] = (red[0][tid] + red[1][tid] + red[2][tid] + red[3][tid]) * (1.f / NPG);
    __syncthreads();
    if (tid < 128) {
        int d = tid;
        float a = b3[d];
#pragma unroll 8
        for (int k = 0; k < 64; ++k) a += ps[k] * W3[k * DD + d];
        float freq = expf((float)(d & ~1) * (-9.210340371976184f / 128.f));
        float ang = (float)(g & (TT - 1)) * freq;
        a += (d & 1) ? cosf(ang) : sinf(ang);
        seq[(size_t)g * DD + d] = a;
    }
}

// ---------------- Transformer (row-major, tiled GEMMs, fused LN) ----------------

template <int BM, int BN, int BK, int K, bool RELU, bool RESLN>
__global__ __launch_bounds__(256) void k_gemm(
    const float* __restrict__ A, const float* __restrict__ W,
    const float* __restrict__ bias, const float* __restrict__ res,
    const float* __restrict__ lng, const float* __restrict__ lnb,
    float* __restrict__ C, int N) {
    constexpr int TX = BN / 4;
    constexpr int TY = 256 / TX;
    constexpr int MR = BM / TY;
    __shared__ float as[BK][BM + 4];
    __shared__ float ws[BK][BN + 4];
    __shared__ float smc[RESLN ? BM * (BN + 4) : 4];
    int tid = threadIdx.x;
    int r0 = blockIdx.y * BM, c0 = blockIdx.x * BN;
    int tx = tid % TX, ty = tid / TX;
    float acc[MR][4] = {};
    for (int k0 = 0; k0 < K; k0 += BK) {
        for (int li = tid; li < BM * BK / 4; li += 256) {
            int r = li / (BK / 4), kq = li % (BK / 4);
            float4 v = *(const float4*)&A[(size_t)(r0 + r) * K + k0 + kq * 4];
            as[kq * 4 + 0][r] = v.x; as[kq * 4 + 1][r] = v.y;
            as[kq * 4 + 2][r] = v.z; as[kq * 4 + 3][r] = v.w;
        }
        for (int li = tid; li < BN * BK / 4; li += 256) {
            int cc = li / (BK / 4), kq = li % (BK / 4);
            float4 v = *(const float4*)&W[(size_t)(c0 + cc) * K + k0 + kq * 4];
            ws[kq * 4 + 0][cc] = v.x; ws[kq * 4 + 1][cc] = v.y;
            ws[kq * 4 + 2][cc] = v.z; ws[kq * 4 + 3][cc] = v.w;
        }
        __syncthreads();
#pragma unroll
        for (int k = 0; k < BK; ++k) {
            float4 wv = *(const float4*)&ws[k][tx * 4];
            float w4[4] = {wv.x, wv.y, wv.z, wv.w};
#pragma unroll
            for (int i = 0; i < MR; ++i) {
                float a = as[k][ty * MR + i];
#pragma unroll
                for (int j = 0; j < 4; ++j) acc[i][j] += a * w4[j];
            }
        }
        __syncthreads();
    }
    float4 bv = *(const float4*)&bias[c0 + tx * 4];
    float b4[4] = {bv.x, bv.y, bv.z, bv.w};
    if constexpr (!RESLN) {
#pragma unroll
        for (int i = 0; i < MR; ++i) {
            float4 o;
            o.x = acc[i][0] + b4[0]; o.y = acc[i][1] + b4[1];
            o.z = acc[i][2] + b4[2]; o.w = acc[i][3] + b4[3];
            if (RELU) {
                o.x = fmaxf(o.x, 0.f); o.y = fmaxf(o.y, 0.f);
                o.z = fmaxf(o.z, 0.f); o.w = fmaxf(o.w, 0.f);
            }
            *(float4*)&C[(size_t)(r0 + ty * MR + i) * N + c0 + tx * 4] = o;
        }
    } else {
        float(*sm)[BN + 4] = (float(*)[BN + 4])smc;
#pragma unroll
        for (int i = 0; i < MR; ++i) {
            float4 r4 = *(const float4*)&res[(size_t)(r0 + ty * MR + i) * N + tx * 4];
            sm[ty * MR + i][tx * 4 + 0] = acc[i][0] + b4[0] + r4.x;
            sm[ty * MR + i][tx * 4 + 1] = acc[i][1] + b4[1] + r4.y;
            sm[ty * MR + i][tx * 4 + 2] = acc[i][2] + b4[2] + r4.z;
            sm[ty * MR + i][tx * 4 + 3] = acc[i][3] + b4[3] + r4.w;
        }
        __syncthreads();
        int wv_ = tid >> 6, ln = tid & 63;
        for (int r = wv_ * (BM / 4); r < (wv_ + 1) * (BM / 4); ++r) {
            float v0 = sm[r][ln], v1 = sm[r][ln + 64];
            float s = v0 + v1, q = v0 * v0 + v1 * v1;
            wave_sum64_2(s, q);
            float mean = s * (1.f / 128.f);
            float var = q * (1.f / 128.f) - mean * mean;
            float rstd = rsqrtf(var + 1e-5f);
            C[(size_t)(r0 + r) * N + ln] = (v0 - mean) * rstd * lng[ln] + lnb[ln];
            C[(size_t)(r0 + r) * N + ln + 64] =
                (v1 - mean) * rstd * lng[ln + 64] + lnb[ln + 64];
        }
    }
}

// attention: block per (b,h), 256 threads
__global__ __launch_bounds__(256) void k_attn(const float* __restrict__ qkv,
                                              float* __restrict__ abuf) {
    int b = blockIdx.x >> 2, h = blockIdx.x & 3;
    __shared__ float Qs[64][36], Ks[64][36], Vs[64][36];
    __shared__ float Ss[64][68];
    int tid = threadIdx.x;
    const float* base = qkv + (size_t)(b * 64) * 384 + h * 32;
    for (int li = tid; li < 512; li += 256) {
        int r = li >> 3, dq = li & 7;
        *(float4*)&Qs[r][dq * 4] = *(const float4*)&base[(size_t)r * 384 + dq * 4];
        *(float4*)&Ks[r][dq * 4] = *(const float4*)&base[(size_t)r * 384 + 128 + dq * 4];
        *(float4*)&Vs[r][dq * 4] = *(const float4*)&base[(size_t)r * 384 + 256 + dq * 4];
    }
    __syncthreads();
    int q = tid >> 2, kg = tid & 3;
    const float scale = 0.17677669529663687f;  // 1/sqrt(32)
    float p[16];
    float mx = -1e30f;
#pragma unroll
    for (int kk = 0; kk < 16; ++kk) {
        int k = kg * 16 + kk;
        float a = 0.f;
#pragma unroll
        for (int dq = 0; dq < 8; ++dq) {
            float4 qv = *(const float4*)&Qs[q][dq * 4];
            float4 kv = *(const float4*)&Ks[k][dq * 4];
            a += qv.x * kv.x + qv.y * kv.y + qv.z * kv.z + qv.w * kv.w;
        }
        p[kk] = a * scale;
        mx = fmaxf(mx, p[kk]);
    }
    mx = fmaxf(mx, __shfl_xor(mx, 1));
    mx = fmaxf(mx, __shfl_xor(mx, 2));
    float ssum = 0.f;
#pragma unroll
    for (int kk = 0; kk < 16; ++kk) {
        p[kk] = expf(p[kk] - mx);
        ssum += p[kk];
    }
    ssum += __shfl_xor(ssum, 1);
    ssum += __shfl_xor(ssum, 2);
    float inv = 1.f / ssum;
#pragma unroll
    for (int kk = 0; kk < 16; ++kk) Ss[q][kg * 16 + kk] = p[kk] * inv;
    __syncthreads();
    int dg = kg;
    float o[8] = {};
    for (int k = 0; k < 64; ++k) {
        float pw = Ss[q][k];
        float4 v0 = *(const float4*)&Vs[k][dg * 8];
        float4 v1 = *(const float4*)&Vs[k][dg * 8 + 4];
        o[0] += pw * v0.x; o[1] += pw * v0.y; o[2] += pw * v0.z; o[3] += pw * v0.w;
        o[4] += pw * v1.x; o[5] += pw * v1.y; o[6] += pw * v1.z; o[7] += pw * v1.w;
    }
    float* op = abuf + (size_t)(b * 64 + q) * DD + h * 32 + dg * 8;
    *(float4*)&op[0] = make_float4(o[0], o[1], o[2], o[3]);
    *(float4*)&op[4] = make_float4(o[4], o[5], o[6], o[7]);
}

__global__ __launch_bounds__(128) void k_head(
    const float* __restrict__ seq, const float* __restrict__ W1,
    const float* __restrict__ b1, const float* __restrict__ W2,
    const float* __restrict__ b2, float* __restrict__ out) {
    int b = blockIdx.x, t = threadIdx.x;
    __shared__ float pooled[DD];
    __shared__ float hid[64];
    float s = 0.f;
    for (int i = 0; i < TT; ++i) s += seq[(size_t)(b * TT + i) * DD + t];
    pooled[t] = s * (1.f / TT);
    __syncthreads();
    if (t < 64) {
        float a = b1[t];
        const float* wr = W1 + t * DD;
        for (int k = 0; k < DD; ++k) a += pooled[k] * wr[k];
        hid[t] = fmaxf(a, 0.f);
    }
    __syncthreads();
    if (t < 2) {
        float a = b2[t];
        const float* wr = W2 + t * 64;
        for (int k = 0; k < 64; ++k) a += hid[k] * wr[k];
        out[b * 2 + t] = a;
    }
}

// ---------------- host ----------------

extern "C" void kernel_launch(void* const* d_in, const int* in_sizes, int n_in,
                              void* d_out, int out_size, void* d_ws, size_t ws_size,
                              hipStream_t stream) {
    const float* x     = (const float*)d_in[0];
    const int*   esrc  = (const int*)d_in[1];
    const int*   edst  = (const int*)d_in[2];
    const float* gW1   = (const float*)d_in[4];
    const float* gb1   = (const float*)d_in[5];
    const float* ln1g  = (const float*)d_in[6];
    const float* ln1b  = (const float*)d_in[7];
    const float* gW2   = (const float*)d_in[8];
    const float* gb2   = (const float*)d_in[9];
    const float* ln2g  = (const float*)d_in[10];
    const float* ln2b  = (const float*)d_in[11];
    const float* gW3   = (const float*)d_in[12];
    const float* gb3   = (const float*)d_in[13];
    const float* tWqkv = (const float*)d_in[14];
    const float* tbqkv = (const float*)d_in[15];
    const float* tWo   = (const float*)d_in[16];
    const float* tbo   = (const float*)d_in[17];
    const float* tg1   = (const float*)d_in[18];
    const float* tb1   = (const float*)d_in[19];
    const float* tg2   = (const float*)d_in[20];
    const float* tb2   = (const float*)d_in[21];
    const float* tWf1  = (const float*)d_in[22];
    const float* tbf1  = (const float*)d_in[23];
    const float* tWf2  = (const float*)d_in[24];
    const float* tbf2  = (const float*)d_in[25];
    const float* hW1   = (const float*)d_in[26];
    const float* hb1   = (const float*)d_in[27];
    const float* hW2   = (const float*)d_in[28];
    const float* hb2   = (const float*)d_in[29];
    float* out = (float*)d_out;

    int*   hist   = (int*)d_ws;                // 64*512
    int*   off2   = hist + 64 * GG;            // 64*512
    int*   goff   = off2 + 64 * GG;            // 513 (pad 516)
    int*   node_off = goff + 516;              // NN+1 (pad NN+4)
    uint*  gpack  = (uint*)(node_off + NN + 4);// EE
    uint2* epackN = (uint2*)(gpack + EE);      // EE (16B-aligned: offsets even)
    float* deginv = (float*)(epackN + EE);     // NN
    float* wgtv   = deginv + NN;               // NN
    float2* aggx  = (float2*)(wgtv + NN);      // NN
    float* bufA = (float*)(aggx + NN);         // NN*64
    float* bufB = bufA + (size_t)NN * 64;      // NN*64
    float* seq  = bufB + (size_t)NN * 64;      // 512*128
    float* qkvb = seq + GG * DD;               // 512*384
    float* abuf = qkvb + GG * 384;             // 512*128
    float* f1b  = abuf + GG * DD;              // 512*512

    // CSR build: coalesced counting sort (no global atomics)
    k_a1<<<64, 256, 0, stream>>>(esrc, hist);
    k_a2<<<1, 512, 0, stream>>>(hist, off2, goff);
    k_a3<<<64, 256, 0, stream>>>(esrc, edst, off2, gpack);
    k_bsort<<<GG, 256, 0, stream>>>(x, goff, gpack, epackN, node_off, deginv, wgtv, aggx);

    // GCN
    k_gcn1t<<<NN / 64, 256, 0, stream>>>(aggx, gW1, gb1, ln1g, ln1b, bufA);
    k_agg_lin_ln<<<NN / 50, 256, 0, stream>>>(bufA, gW2, gb2, ln2g, ln2b, deginv,
                                              node_off, epackN, bufB);
    k_wpool_emb<<<GG, 256, 0, stream>>>(bufB, wgtv, gW3, gb3, seq);

    // Transformer (row-major)
    for (int l = 0; l < LL; l++) {
        k_gemm<32, 32, 32, 128, false, false><<<dim3(12, 16), 256, 0, stream>>>(
            seq, tWqkv + (size_t)l * 384 * 128, tbqkv + l * 384,
            nullptr, nullptr, nullptr, qkvb, 384);
        k_attn<<<BB * 4, 256, 0, stream>>>(qkvb, abuf);
        k_gemm<8, 128, 32, 128, false, true><<<dim3(1, 64), 256, 0, stream>>>(
            abuf, tWo + (size_t)l * 128 * 128, tbo + l * 128,
            seq, tg1 + l * 128, tb1 + l * 128, seq, 128);
        k_gemm<32, 32, 32, 128, true, false><<<dim3(16, 16), 256, 0, stream>>>(
            seq, tWf1 + (size_t)l * 512 * 128, tbf1 + l * 512,
            nullptr, nullptr, nullptr, f1b, 512);
        k_gemm<8, 128, 32, 512, false, true><<<dim3(1, 64), 256, 0, stream>>>(
            f1b, tWf2 + (size_t)l * 128 * 512, tbf2 + l * 128,
            seq, tg2 + l * 128, tb2 + l * 128, seq, 128);
    }

    // head
    k_head<<<BB, DD, 0, stream>>>(seq, hW1, hb1, hW2, hb2, out);
}